// Round 5
// baseline (1708.416 us; speedup 1.0000x reference)
//
#include <hip/hip_runtime.h>
#include <hip/hip_bf16.h>
#include <math.h>

#define N_NODES 100000
#define N_EDGES 1600000
#define N_GRAPHS 64
#define IN_CH 128
#define DIM 64
#define EDGE_DIM 7
#define N_CONVS 3
#define NBLK 196  // ceil(100000/512)

typedef const float* fp;

// ---------------- CSR build ----------------
__global__ __launch_bounds__(256) void count_kernel(const int* __restrict__ dst, int* __restrict__ cnt) {
    int j = blockIdx.x * 256 + threadIdx.x;
    if (j < N_EDGES) {
        int d = dst[j];
        if ((unsigned)d < N_NODES) atomicAdd(&cnt[d], 1);
    }
}

__global__ __launch_bounds__(512) void scan1_kernel(const int* __restrict__ cnt, int* __restrict__ rp,
                                                    int* __restrict__ blksum) {
    __shared__ int tmp[512];
    int t = threadIdx.x, i = blockIdx.x * 512 + t;
    int v0 = (i < N_NODES) ? cnt[i] : 0;
    tmp[t] = v0;
    __syncthreads();
    for (int off = 1; off < 512; off <<= 1) {
        int add = (t >= off) ? tmp[t - off] : 0;
        __syncthreads();
        tmp[t] += add;
        __syncthreads();
    }
    if (i < N_NODES) rp[i] = tmp[t] - v0;  // exclusive within block
    if (t == 511) blksum[blockIdx.x] = tmp[511];
}

__global__ __launch_bounds__(256) void scan2_kernel(int* __restrict__ blksum) {
    __shared__ int tmp[256];
    int t = threadIdx.x;
    int v0 = (t < NBLK) ? blksum[t] : 0;
    tmp[t] = v0;
    __syncthreads();
    for (int off = 1; off < 256; off <<= 1) {
        int add = (t >= off) ? tmp[t - off] : 0;
        __syncthreads();
        tmp[t] += add;
        __syncthreads();
    }
    if (t < NBLK) blksum[t] = tmp[t] - v0;  // exclusive
}

__global__ __launch_bounds__(512) void scan3_kernel(int* __restrict__ rp, const int* __restrict__ blksum,
                                                    int* __restrict__ cursor) {
    int t = threadIdx.x, i = blockIdx.x * 512 + t;
    if (i < N_NODES) {
        int v = rp[i] + blksum[blockIdx.x];
        rp[i] = v;
        cursor[i] = v;
    }
    if (i == 0) rp[N_NODES] = N_EDGES;
}

__global__ __launch_bounds__(256) void scatter_kernel(const int* __restrict__ src, const int* __restrict__ dst,
                                                      int* __restrict__ cursor, int* __restrict__ csr_src,
                                                      int* __restrict__ csr_eid) {
    int j = blockIdx.x * 256 + threadIdx.x;
    if (j < N_EDGES) {
        int d = dst[j];
        if ((unsigned)d >= N_NODES) return;
        int pos = atomicAdd(&cursor[d], 1);
        if ((unsigned)pos < N_EDGES) {
            int s = src[j];
            csr_src[pos] = ((unsigned)s < N_NODES) ? s : 0;
            csr_eid[pos] = j;
        }
    }
}

// ---------------- node-feature GEMMs (q,k,v,skip) ----------------
template <int IN>
__global__ __launch_bounds__(256) void gemm4_kernel(
    const float* __restrict__ h,
    fp W0, fp B0, fp W1, fp B1, fp W2, fp B2, fp W3, fp B3,
    float* __restrict__ O0, float* __restrict__ O1, float* __restrict__ O2, float* __restrict__ O3) {
    __shared__ float hs[16][IN];
    int mat = blockIdx.y;
    fp W = mat == 0 ? W0 : mat == 1 ? W1 : mat == 2 ? W2 : W3;
    fp B = mat == 0 ? B0 : mat == 1 ? B1 : mat == 2 ? B2 : B3;
    float* O = mat == 0 ? O0 : mat == 1 ? O1 : mat == 2 ? O2 : O3;
    int row0 = blockIdx.x * 16;  // N_NODES % 16 == 0
    for (int idx = threadIdx.x; idx < 16 * IN; idx += 256) {
        int r = idx / IN, c = idx - r * IN;
        hs[r][c] = h[(size_t)(row0 + r) * IN + c];
    }
    __syncthreads();
    int c = threadIdx.x & 63, rg = threadIdx.x >> 6;  // 4 row-groups
    float a0 = 0.f, a1 = 0.f, a2 = 0.f, a3 = 0.f;
    for (int kk = 0; kk < IN; ++kk) {
        float wv = W[kk * 64 + c];
        a0 += hs[rg + 0][kk] * wv;
        a1 += hs[rg + 4][kk] * wv;
        a2 += hs[rg + 8][kk] * wv;
        a3 += hs[rg + 12][kk] * wv;
    }
    float bb = B[c];
    O[(size_t)(row0 + rg + 0) * 64 + c] = a0 + bb;
    O[(size_t)(row0 + rg + 4) * 64 + c] = a1 + bb;
    O[(size_t)(row0 + rg + 8) * 64 + c] = a2 + bb;
    O[(size_t)(row0 + rg + 12) * 64 + c] = a3 + bb;
}

// ---------------- per-node edge aggregation (online softmax) ----------------
__global__ __launch_bounds__(256) void node_kernel(
    const float* __restrict__ q, const float* __restrict__ k, const float* __restrict__ v,
    const float* __restrict__ sk, fp edge_attr, fp We,
    const int* __restrict__ row_ptr, const int* __restrict__ csr_src, const int* __restrict__ csr_eid,
    float* __restrict__ h_out, float* __restrict__ hmax, int act, int initmax) {
    int n = (blockIdx.x * 256 + threadIdx.x) >> 6;  // wave per node; N_NODES*64 % 256 == 0
    int lane = threadIdx.x & 63;
    float qf = q[(size_t)n * 64 + lane];
    float we[7];
#pragma unroll
    for (int c = 0; c < 7; ++c) we[c] = We[c * 64 + lane];
    int beg = row_ptr[n], end = row_ptr[n + 1];
    float m = -INFINITY, s = 0.f, acc = 0.f;
    for (int p = beg; p < end; ++p) {
        int sn = csr_src[p];
        int eid = csr_eid[p];
        fp ea = edge_attr + (size_t)eid * 7;
        float e = we[0] * ea[0];
#pragma unroll
        for (int c = 1; c < 7; ++c) e += we[c] * ea[c];
        float kf = k[(size_t)sn * 64 + lane];
        float vf = v[(size_t)sn * 64 + lane];
        float al = qf * (kf + e);
#pragma unroll
        for (int off = 32; off; off >>= 1) al += __shfl_xor(al, off);
        al *= 0.125f;  // 1/sqrt(64)
        float mn = fmaxf(m, al);
        float co = __expf(m - mn);   // 0 when m was -inf
        float pe = __expf(al - mn);
        s = s * co + pe;
        acc = acc * co + pe * (vf + e);
        m = mn;
    }
    float out = acc / (s + 1e-16f) + sk[(size_t)n * 64 + lane];
    if (act) out = out > 0.f ? out : (__expf(out) - 1.f);  // ELU
    h_out[(size_t)n * 64 + lane] = out;
    float hm = initmax ? out : fmaxf(hmax[(size_t)n * 64 + lane], out);
    hmax[(size_t)n * 64 + lane] = hm;
}

// ---------------- gate MLP per node ----------------
__global__ __launch_bounds__(256) void gate_kernel(const float* __restrict__ h, fp g1W, fp g1b, fp g2W,
                                                   fp g2b, float* __restrict__ gate) {
    __shared__ float hs[4][64];
    int w = threadIdx.x >> 6, lane = threadIdx.x & 63;
    int n = blockIdx.x * 4 + w;  // N_NODES % 4 == 0
    hs[w][lane] = h[(size_t)n * 64 + lane];
    __syncthreads();
    float a = 0.f;
    for (int f = 0; f < 64; ++f) a += hs[w][f] * g1W[f * 64 + lane];
    a = fmaxf(a + g1b[lane], 0.f);
    float val = a * g2W[lane];
#pragma unroll
    for (int off = 32; off; off >>= 1) val += __shfl_xor(val, off);
    if (lane == 0) gate[n] = val + g2b[0];
}

// ---------------- graph boundaries (batch sorted) ----------------
__global__ __launch_bounds__(256) void starts_kernel(const int* __restrict__ batch, int* __restrict__ starts) {
    int i = blockIdx.x * 256 + threadIdx.x;
    if (i >= N_NODES) return;
    if (i == 0) {
        int b = batch[0];
        for (int g = 0; g <= b && g <= N_GRAPHS; ++g) starts[g] = 0;
    } else {
        int b0 = batch[i - 1], b1 = batch[i];
        for (int g = b0 + 1; g <= b1 && g <= N_GRAPHS; ++g) starts[g] = i;
    }
    if (i == N_NODES - 1) {
        int b = batch[i];
        for (int g = b + 1; g <= N_GRAPHS; ++g) starts[g] = N_NODES;
    }
}

// ---------------- gated softmax pooling, one block per graph ----------------
__global__ __launch_bounds__(256) void pool_kernel(const float* __restrict__ h, const float* __restrict__ gate,
                                                   const int* __restrict__ starts, float* __restrict__ pooled) {
    int g = blockIdx.x;
    int beg = starts[g], end = starts[g + 1];
    int tid = threadIdx.x, lane = tid & 63, w = tid >> 6;
    __shared__ float red[4];
    __shared__ float accs[4][64];
    float m = -INFINITY;
    for (int i = beg + tid; i < end; i += 256) m = fmaxf(m, gate[i]);
#pragma unroll
    for (int off = 32; off; off >>= 1) m = fmaxf(m, __shfl_xor(m, off));
    if (lane == 0) red[w] = m;
    __syncthreads();
    m = fmaxf(fmaxf(red[0], red[1]), fmaxf(red[2], red[3]));
    __syncthreads();
    float s = 0.f;
    for (int i = beg + tid; i < end; i += 256) s += __expf(gate[i] - m);
#pragma unroll
    for (int off = 32; off; off >>= 1) s += __shfl_xor(s, off);
    if (lane == 0) red[w] = s;
    __syncthreads();
    s = red[0] + red[1] + red[2] + red[3] + 1e-16f;
    float acc = 0.f;
    for (int i = beg + w; i < end; i += 4) {
        float p = __expf(gate[i] - m);
        acc += p * h[(size_t)i * 64 + lane];
    }
    accs[w][lane] = acc;
    __syncthreads();
    if (w == 0) pooled[g * 64 + lane] = (accs[0][lane] + accs[1][lane] + accs[2][lane] + accs[3][lane]) / s;
}

// ---------------- 6-expert MLP head, one block per expert (f32 output) ----------------
__global__ __launch_bounds__(256) void mlp_kernel(const float* __restrict__ pooled, fp m0W, fp m0b, fp m1W,
                                                  fp m1b, fp m2W, fp m2b, fp m3W, fp m3b,
                                                  float* __restrict__ out) {
    int e = blockIdx.x, tid = threadIdx.x;
    __shared__ float P[64 * 64];
    __shared__ float A1[64 * 32];
    __shared__ float A2[64 * 16];
    __shared__ float A3[64 * 8];
    for (int i = tid; i < 64 * 64; i += 256) P[i] = pooled[i];
    __syncthreads();
    fp W0 = m0W + e * 64 * 32; fp B0 = m0b + e * 32;
    for (int i = tid; i < 64 * 32; i += 256) {
        int g = i >> 5, c = i & 31;
        float a = B0[c];
        for (int f = 0; f < 64; ++f) a += P[g * 64 + f] * W0[f * 32 + c];
        A1[i] = a > 0.f ? a : (__expf(a) - 1.f);
    }
    __syncthreads();
    fp W1 = m1W + e * 32 * 16; fp B1 = m1b + e * 16;
    for (int i = tid; i < 64 * 16; i += 256) {
        int g = i >> 4, c = i & 15;
        float a = B1[c];
        for (int f = 0; f < 32; ++f) a += A1[g * 32 + f] * W1[f * 16 + c];
        A2[i] = a > 0.f ? a : (__expf(a) - 1.f);
    }
    __syncthreads();
    fp W2 = m2W + e * 16 * 8; fp B2 = m2b + e * 8;
    for (int i = tid; i < 64 * 8; i += 256) {
        int g = i >> 3, c = i & 7;
        float a = B2[c];
        for (int f = 0; f < 16; ++f) a += A2[g * 16 + f] * W2[f * 8 + c];
        A3[i] = a > 0.f ? a : (__expf(a) - 1.f);
    }
    __syncthreads();
    fp W3 = m3W + e * 8;
    if (tid < 64) {
        int g = tid;
        float a = m3b[e];
        for (int j = 0; j < 8; ++j) a += A3[g * 8 + j] * W3[j];
        out[g * 6 + e] = a;  // preds [G,6] as float32
    }
}

__global__ __launch_bounds__(64) void loss_kernel(const float* __restrict__ preds, fp y,
                                                  float* __restrict__ out) {
    int lane = threadIdx.x;
    float lsum = 0.f;
    if (lane < 6) {
        float acc = 0.f;
        for (int g = 0; g < 64; ++g) {
            float d = preds[g * 6 + lane] - y[g * 6 + lane];
            acc += d * d;
        }
        lsum = sqrtf(acc / 64.f);
    }
#pragma unroll
    for (int off = 32; off; off >>= 1) lsum += __shfl_xor(lsum, off);
    if (lane == 0) out[384] = lsum;  // total_loss (float32) right after preds[64*6]
}

extern "C" void kernel_launch(void* const* d_in, const int* in_sizes, int n_in, void* d_out, int out_size,
                              void* d_ws, size_t ws_size, hipStream_t stream) {
    // Inputs follow setup_inputs() dict order: x, edge_index, edge_attr, batch, y, <30 weights>.
    // Float tensors are float32 (98 MB npz rules out bf16); OUTPUT dtype = reference output dtype = float32.
    bool dictOrder = (in_sizes[1] == 2 * N_EDGES);
    int iEI = dictOrder ? 1 : 33;
    int iEA = dictOrder ? 2 : 1;
    int iBT = dictOrder ? 3 : 34;
    int iY  = dictOrder ? 4 : 2;
    int w0  = dictOrder ? 5 : 3;  // first weight (Wq0)

    fp x = (fp)d_in[0];
    const int* ei = (const int*)d_in[iEI];
    fp eattr = (fp)d_in[iEA];
    const int* batch = (const int*)d_in[iBT];
    fp y = (fp)d_in[iY];
    fp Wq0 = (fp)d_in[w0 + 0], bq0 = (fp)d_in[w0 + 1], Wk0 = (fp)d_in[w0 + 2], bk0 = (fp)d_in[w0 + 3];
    fp Wv0 = (fp)d_in[w0 + 4], bv0 = (fp)d_in[w0 + 5], We0 = (fp)d_in[w0 + 6];
    fp Ws0 = (fp)d_in[w0 + 7], bs0 = (fp)d_in[w0 + 8];
    fp Wq = (fp)d_in[w0 + 9], bq = (fp)d_in[w0 + 10], Wk = (fp)d_in[w0 + 11], bk = (fp)d_in[w0 + 12];
    fp Wv = (fp)d_in[w0 + 13], bv = (fp)d_in[w0 + 14], Wel = (fp)d_in[w0 + 15];
    fp Ws = (fp)d_in[w0 + 16], bs = (fp)d_in[w0 + 17];
    fp g1W = (fp)d_in[w0 + 18], g1b = (fp)d_in[w0 + 19], g2W = (fp)d_in[w0 + 20], g2b = (fp)d_in[w0 + 21];
    fp m0W = (fp)d_in[w0 + 22], m0b = (fp)d_in[w0 + 23], m1W = (fp)d_in[w0 + 24], m1b = (fp)d_in[w0 + 25];
    fp m2W = (fp)d_in[w0 + 26], m2b = (fp)d_in[w0 + 27], m3W = (fp)d_in[w0 + 28], m3b = (fp)d_in[w0 + 29];

    const int* srcArr = ei;
    const int* dstArr = ei + N_EDGES;

    char* wsp = (char*)d_ws;
    auto alloc = [&](size_t bytes) -> void* {
        void* p = (void*)wsp;
        wsp += (bytes + 255) & ~(size_t)255;
        return p;
    };
    float* q = (float*)alloc((size_t)N_NODES * 64 * 4);
    float* kb = (float*)alloc((size_t)N_NODES * 64 * 4);
    float* vb = (float*)alloc((size_t)N_NODES * 64 * 4);
    float* skb = (float*)alloc((size_t)N_NODES * 64 * 4);
    float* hbuf = (float*)alloc((size_t)N_NODES * 64 * 4);
    float* hmax = (float*)alloc((size_t)N_NODES * 64 * 4);
    float* gate = (float*)alloc((size_t)N_NODES * 4);
    float* pooled = (float*)alloc(64 * 64 * 4);
    int* row_ptr = (int*)alloc((N_NODES + 1) * 4);
    int* cursor = (int*)alloc((size_t)N_NODES * 4);
    int* csr_src = (int*)alloc((size_t)N_EDGES * 4);
    int* csr_eid = (int*)alloc((size_t)N_EDGES * 4);
    int* blksum = (int*)alloc(256 * 4);
    int* starts = (int*)alloc((N_GRAPHS + 1) * 4);
    (void)ws_size;
    (void)n_in;

    float* outF = (float*)d_out;  // [0..383] preds, [384] total_loss

    // ---- CSR build (by dst) ----
    hipMemsetAsync(cursor, 0, (size_t)N_NODES * 4, stream);
    count_kernel<<<(N_EDGES + 255) / 256, 256, 0, stream>>>(dstArr, cursor);
    scan1_kernel<<<NBLK, 512, 0, stream>>>(cursor, row_ptr, blksum);
    scan2_kernel<<<1, 256, 0, stream>>>(blksum);
    scan3_kernel<<<NBLK, 512, 0, stream>>>(row_ptr, blksum, cursor);
    scatter_kernel<<<(N_EDGES + 255) / 256, 256, 0, stream>>>(srcArr, dstArr, cursor, csr_src, csr_eid);

    dim3 gg(N_NODES / 16, 4);
    // layer 0 (conv_first, 128 -> 64), ELU, init hmax
    gemm4_kernel<IN_CH><<<gg, 256, 0, stream>>>(x, Wq0, bq0, Wk0, bk0, Wv0, bv0, Ws0, bs0,
                                                q, kb, vb, skb);
    node_kernel<<<N_NODES * 64 / 256, 256, 0, stream>>>(q, kb, vb, skb, eattr, We0, row_ptr, csr_src, csr_eid,
                                                        hbuf, hmax, 1, 1);
    // layers 1..3 (64 -> 64); ELU except last; JK running max
    for (int i = 0; i < N_CONVS; ++i) {
        gemm4_kernel<DIM><<<gg, 256, 0, stream>>>(hbuf, Wq + i * 4096, bq + i * 64, Wk + i * 4096,
                                                  bk + i * 64, Wv + i * 4096, bv + i * 64, Ws + i * 4096,
                                                  bs + i * 64, q, kb, vb, skb);
        node_kernel<<<N_NODES * 64 / 256, 256, 0, stream>>>(q, kb, vb, skb, eattr, Wel + i * 448, row_ptr,
                                                            csr_src, csr_eid, hbuf, hmax,
                                                            (i < N_CONVS - 1) ? 1 : 0, 0);
    }
    // pooling head
    gate_kernel<<<N_NODES / 4, 256, 0, stream>>>(hmax, g1W, g1b, g2W, g2b, gate);
    starts_kernel<<<(N_NODES + 255) / 256, 256, 0, stream>>>(batch, starts);
    pool_kernel<<<N_GRAPHS, 256, 0, stream>>>(hmax, gate, starts, pooled);
    mlp_kernel<<<6, 256, 0, stream>>>(pooled, m0W, m0b, m1W, m1b, m2W, m2b, m3W, m3b, outF);
    loss_kernel<<<1, 64, 0, stream>>>(outF, y, outF);
}

// Round 7
// 1560.576 us; speedup vs baseline: 1.0947x; 1.0947x over previous
//
#include <hip/hip_runtime.h>
#include <hip/hip_bf16.h>
#include <math.h>

#define N_NODES 100000
#define N_EDGES 1600000
#define N_GRAPHS 64
#define IN_CH 128
#define DIM 64
#define EDGE_DIM 7
#define N_CONVS 3
#define NBLK 196  // ceil(100000/512)

typedef const float* fp;

// ---------------- CSR build ----------------
__global__ __launch_bounds__(256) void count_kernel(const int* __restrict__ dst, int* __restrict__ cnt) {
    int j = blockIdx.x * 256 + threadIdx.x;
    if (j < N_EDGES) {
        int d = dst[j];
        if ((unsigned)d < N_NODES) atomicAdd(&cnt[d], 1);
    }
}

__global__ __launch_bounds__(512) void scan1_kernel(const int* __restrict__ cnt, int* __restrict__ rp,
                                                    int* __restrict__ blksum) {
    __shared__ int tmp[512];
    int t = threadIdx.x, i = blockIdx.x * 512 + t;
    int v0 = (i < N_NODES) ? cnt[i] : 0;
    tmp[t] = v0;
    __syncthreads();
    for (int off = 1; off < 512; off <<= 1) {
        int add = (t >= off) ? tmp[t - off] : 0;
        __syncthreads();
        tmp[t] += add;
        __syncthreads();
    }
    if (i < N_NODES) rp[i] = tmp[t] - v0;  // exclusive within block
    if (t == 511) blksum[blockIdx.x] = tmp[511];
}

__global__ __launch_bounds__(256) void scan2_kernel(int* __restrict__ blksum) {
    __shared__ int tmp[256];
    int t = threadIdx.x;
    int v0 = (t < NBLK) ? blksum[t] : 0;
    tmp[t] = v0;
    __syncthreads();
    for (int off = 1; off < 256; off <<= 1) {
        int add = (t >= off) ? tmp[t - off] : 0;
        __syncthreads();
        tmp[t] += add;
        __syncthreads();
    }
    if (t < NBLK) blksum[t] = tmp[t] - v0;  // exclusive
}

__global__ __launch_bounds__(512) void scan3_kernel(int* __restrict__ rp, const int* __restrict__ blksum,
                                                    int* __restrict__ cursor) {
    int t = threadIdx.x, i = blockIdx.x * 512 + t;
    if (i < N_NODES) {
        int v = rp[i] + blksum[blockIdx.x];
        rp[i] = v;
        cursor[i] = v;
    }
    if (i == 0) rp[N_NODES] = N_EDGES;
}

__global__ __launch_bounds__(256) void scatter_kernel(const int* __restrict__ src, const int* __restrict__ dst,
                                                      int* __restrict__ cursor, int* __restrict__ csr_src,
                                                      int* __restrict__ csr_eid) {
    int j = blockIdx.x * 256 + threadIdx.x;
    if (j < N_EDGES) {
        int d = dst[j];
        if ((unsigned)d >= N_NODES) return;
        int pos = atomicAdd(&cursor[d], 1);
        if ((unsigned)pos < N_EDGES) {
            int s = src[j];
            csr_src[pos] = ((unsigned)s < N_NODES) ? s : 0;
            csr_eid[pos] = j;
        }
    }
}

// permute edge_attr into CSR order (reused by all 4 conv layers)
__global__ __launch_bounds__(256) void permute_ea_kernel(fp ea, const int* __restrict__ csr_eid,
                                                         float* __restrict__ ea_csr) {
    int p = blockIdx.x * 256 + threadIdx.x;
    if (p < N_EDGES) {
        int eid = csr_eid[p];
        size_t sb = (size_t)eid * 7, db = (size_t)p * 7;
#pragma unroll
        for (int c = 0; c < 7; ++c) ea_csr[db + c] = ea[sb + c];
    }
}

// ---------------- node-feature GEMMs (q,k,v,skip); per-matrix output stride ----------------
template <int IN>
__global__ __launch_bounds__(256) void gemm4_kernel(
    const float* __restrict__ h,
    fp W0, fp B0, fp W1, fp B1, fp W2, fp B2, fp W3, fp B3,
    float* __restrict__ O0, int ld0, float* __restrict__ O1, int ld1,
    float* __restrict__ O2, int ld2, float* __restrict__ O3, int ld3) {
    __shared__ float hs[16][IN];
    int mat = blockIdx.y;
    fp W = mat == 0 ? W0 : mat == 1 ? W1 : mat == 2 ? W2 : W3;
    fp B = mat == 0 ? B0 : mat == 1 ? B1 : mat == 2 ? B2 : B3;
    float* O = mat == 0 ? O0 : mat == 1 ? O1 : mat == 2 ? O2 : O3;
    int ld = mat == 0 ? ld0 : mat == 1 ? ld1 : mat == 2 ? ld2 : ld3;
    int row0 = blockIdx.x * 16;  // N_NODES % 16 == 0
    for (int idx = threadIdx.x; idx < 16 * IN; idx += 256) {
        int r = idx / IN, c = idx - r * IN;
        hs[r][c] = h[(size_t)(row0 + r) * IN + c];
    }
    __syncthreads();
    int c = threadIdx.x & 63, rg = threadIdx.x >> 6;  // 4 row-groups
    float a0 = 0.f, a1 = 0.f, a2 = 0.f, a3 = 0.f;
    for (int kk = 0; kk < IN; ++kk) {
        float wv = W[kk * 64 + c];
        a0 += hs[rg + 0][kk] * wv;
        a1 += hs[rg + 4][kk] * wv;
        a2 += hs[rg + 8][kk] * wv;
        a3 += hs[rg + 12][kk] * wv;
    }
    float bb = B[c];
    O[(size_t)(row0 + rg + 0) * ld + c] = a0 + bb;
    O[(size_t)(row0 + rg + 4) * ld + c] = a1 + bb;
    O[(size_t)(row0 + rg + 8) * ld + c] = a2 + bb;
    O[(size_t)(row0 + rg + 12) * ld + c] = a3 + bb;
}

// ---------------- per-node edge aggregation (online softmax, ILP-4) ----------------
#define RED64(al)                                              \
    {                                                          \
        _Pragma("unroll") for (int off = 32; off; off >>= 1)   \
            al += __shfl_xor(al, off);                         \
    }

#define UPD(mm, ss, aa, al, vf, e)         \
    {                                      \
        float mn = fmaxf(mm, al);          \
        float co = __expf(mm - mn);        \
        float pe = __expf(al - mn);        \
        ss = ss * co + pe;                 \
        aa = aa * co + pe * ((vf) + (e));  \
        mm = mn;                           \
    }

__global__ __launch_bounds__(256) void node_kernel(
    const float* __restrict__ q, const float* __restrict__ kv, const float* __restrict__ sk,
    const float* __restrict__ ea_csr, fp We,
    const int* __restrict__ row_ptr, const int* __restrict__ csr_src,
    float* __restrict__ h_out, float* __restrict__ hmax, int act, int initmax) {
    int n = (blockIdx.x * 256 + threadIdx.x) >> 6;  // wave per node
    int lane = threadIdx.x & 63;
    float qf = q[(size_t)n * 64 + lane];
    float we[7];
#pragma unroll
    for (int c = 0; c < 7; ++c) we[c] = We[c * 64 + lane];
    int beg = row_ptr[n], end = row_ptr[n + 1];
    float m0 = -INFINITY, m1 = -INFINITY, m2 = -INFINITY, m3 = -INFINITY;
    float s0 = 0.f, s1 = 0.f, s2 = 0.f, s3 = 0.f;
    float a0 = 0.f, a1 = 0.f, a2 = 0.f, a3 = 0.f;
    for (int p0 = beg; p0 < end; p0 += 64) {
        int navail = end - p0;
        if (navail > 64) navail = 64;
        int sn_l = csr_src[p0 + (lane < navail ? lane : navail - 1)];  // coalesced batch load
        int t = 0;
        for (; t + 4 <= navail; t += 4) {
            int sa = __shfl(sn_l, t + 0), sb = __shfl(sn_l, t + 1);
            int sc = __shfl(sn_l, t + 2), sd = __shfl(sn_l, t + 3);
            const float* eb = ea_csr + (size_t)(p0 + t) * 7;
            // 8 independent gathers in flight
            float kfa = kv[(size_t)sa * 128 + lane], vfa = kv[(size_t)sa * 128 + 64 + lane];
            float kfb = kv[(size_t)sb * 128 + lane], vfb = kv[(size_t)sb * 128 + 64 + lane];
            float kfc = kv[(size_t)sc * 128 + lane], vfc = kv[(size_t)sc * 128 + 64 + lane];
            float kfd = kv[(size_t)sd * 128 + lane], vfd = kv[(size_t)sd * 128 + 64 + lane];
            float e0 = we[0] * eb[0], e1 = we[0] * eb[7], e2 = we[0] * eb[14], e3 = we[0] * eb[21];
#pragma unroll
            for (int c = 1; c < 7; ++c) {
                e0 += we[c] * eb[c];
                e1 += we[c] * eb[7 + c];
                e2 += we[c] * eb[14 + c];
                e3 += we[c] * eb[21 + c];
            }
            float al0 = qf * (kfa + e0), al1 = qf * (kfb + e1);
            float al2 = qf * (kfc + e2), al3 = qf * (kfd + e3);
            RED64(al0); RED64(al1); RED64(al2); RED64(al3);
            al0 *= 0.125f; al1 *= 0.125f; al2 *= 0.125f; al3 *= 0.125f;
            UPD(m0, s0, a0, al0, vfa, e0);
            UPD(m1, s1, a1, al1, vfb, e1);
            UPD(m2, s2, a2, al2, vfc, e2);
            UPD(m3, s3, a3, al3, vfd, e3);
        }
        for (; t < navail; ++t) {  // tail into state 0
            int sa = __shfl(sn_l, t);
            const float* eb = ea_csr + (size_t)(p0 + t) * 7;
            float kfa = kv[(size_t)sa * 128 + lane], vfa = kv[(size_t)sa * 128 + 64 + lane];
            float e0 = we[0] * eb[0];
#pragma unroll
            for (int c = 1; c < 7; ++c) e0 += we[c] * eb[c];
            float al0 = qf * (kfa + e0);
            RED64(al0);
            al0 *= 0.125f;
            UPD(m0, s0, a0, al0, vfa, e0);
        }
    }
    // exact merge of 4 online-softmax states
    float M = fmaxf(fmaxf(m0, m1), fmaxf(m2, m3));
    float S = 0.f, A = 0.f;
    if (M > -INFINITY) {
        float w0 = __expf(m0 - M), w1 = __expf(m1 - M), w2 = __expf(m2 - M), w3 = __expf(m3 - M);
        S = s0 * w0 + s1 * w1 + s2 * w2 + s3 * w3;
        A = a0 * w0 + a1 * w1 + a2 * w2 + a3 * w3;
    }
    float out = A / (S + 1e-16f) + sk[(size_t)n * 64 + lane];
    if (act) out = out > 0.f ? out : (__expf(out) - 1.f);  // ELU
    h_out[(size_t)n * 64 + lane] = out;
    float hm = initmax ? out : fmaxf(hmax[(size_t)n * 64 + lane], out);
    hmax[(size_t)n * 64 + lane] = hm;
}

// ---------------- gate MLP per node ----------------
__global__ __launch_bounds__(256) void gate_kernel(const float* __restrict__ h, fp g1W, fp g1b, fp g2W,
                                                   fp g2b, float* __restrict__ gate) {
    __shared__ float hs[4][64];
    int w = threadIdx.x >> 6, lane = threadIdx.x & 63;
    int n = blockIdx.x * 4 + w;  // N_NODES % 4 == 0
    hs[w][lane] = h[(size_t)n * 64 + lane];
    __syncthreads();
    float a = 0.f;
    for (int f = 0; f < 64; ++f) a += hs[w][f] * g1W[f * 64 + lane];
    a = fmaxf(a + g1b[lane], 0.f);
    float val = a * g2W[lane];
#pragma unroll
    for (int off = 32; off; off >>= 1) val += __shfl_xor(val, off);
    if (lane == 0) gate[n] = val + g2b[0];
}

// ---------------- graph boundaries (batch sorted) ----------------
__global__ __launch_bounds__(256) void starts_kernel(const int* __restrict__ batch, int* __restrict__ starts) {
    int i = blockIdx.x * 256 + threadIdx.x;
    if (i >= N_NODES) return;
    if (i == 0) {
        int b = batch[0];
        for (int g = 0; g <= b && g <= N_GRAPHS; ++g) starts[g] = 0;
    } else {
        int b0 = batch[i - 1], b1 = batch[i];
        for (int g = b0 + 1; g <= b1 && g <= N_GRAPHS; ++g) starts[g] = i;
    }
    if (i == N_NODES - 1) {
        int b = batch[i];
        for (int g = b + 1; g <= N_GRAPHS; ++g) starts[g] = N_NODES;
    }
}

// ---------------- gated softmax pooling, one block per graph ----------------
__global__ __launch_bounds__(256) void pool_kernel(const float* __restrict__ h, const float* __restrict__ gate,
                                                   const int* __restrict__ starts, float* __restrict__ pooled) {
    int g = blockIdx.x;
    int beg = starts[g], end = starts[g + 1];
    int tid = threadIdx.x, lane = tid & 63, w = tid >> 6;
    __shared__ float red[4];
    __shared__ float accs[4][64];
    float m = -INFINITY;
    for (int i = beg + tid; i < end; i += 256) m = fmaxf(m, gate[i]);
#pragma unroll
    for (int off = 32; off; off >>= 1) m = fmaxf(m, __shfl_xor(m, off));
    if (lane == 0) red[w] = m;
    __syncthreads();
    m = fmaxf(fmaxf(red[0], red[1]), fmaxf(red[2], red[3]));
    __syncthreads();
    float s = 0.f;
    for (int i = beg + tid; i < end; i += 256) s += __expf(gate[i] - m);
#pragma unroll
    for (int off = 32; off; off >>= 1) s += __shfl_xor(s, off);
    if (lane == 0) red[w] = s;
    __syncthreads();
    s = red[0] + red[1] + red[2] + red[3] + 1e-16f;
    float acc = 0.f;
    for (int i = beg + w; i < end; i += 4) {
        float p = __expf(gate[i] - m);
        acc += p * h[(size_t)i * 64 + lane];
    }
    accs[w][lane] = acc;
    __syncthreads();
    if (w == 0) pooled[g * 64 + lane] = (accs[0][lane] + accs[1][lane] + accs[2][lane] + accs[3][lane]) / s;
}

// ---------------- 6-expert MLP head, one block per expert (f32 output) ----------------
__global__ __launch_bounds__(256) void mlp_kernel(const float* __restrict__ pooled, fp m0W, fp m0b, fp m1W,
                                                  fp m1b, fp m2W, fp m2b, fp m3W, fp m3b,
                                                  float* __restrict__ out) {
    int e = blockIdx.x, tid = threadIdx.x;
    __shared__ float P[64 * 64];
    __shared__ float A1[64 * 32];
    __shared__ float A2[64 * 16];
    __shared__ float A3[64 * 8];
    for (int i = tid; i < 64 * 64; i += 256) P[i] = pooled[i];
    __syncthreads();
    fp W0 = m0W + e * 64 * 32; fp B0 = m0b + e * 32;
    for (int i = tid; i < 64 * 32; i += 256) {
        int g = i >> 5, c = i & 31;
        float a = B0[c];
        for (int f = 0; f < 64; ++f) a += P[g * 64 + f] * W0[f * 32 + c];
        A1[i] = a > 0.f ? a : (__expf(a) - 1.f);
    }
    __syncthreads();
    fp W1 = m1W + e * 32 * 16; fp B1 = m1b + e * 16;
    for (int i = tid; i < 64 * 16; i += 256) {
        int g = i >> 4, c = i & 15;
        float a = B1[c];
        for (int f = 0; f < 32; ++f) a += A1[g * 32 + f] * W1[f * 16 + c];
        A2[i] = a > 0.f ? a : (__expf(a) - 1.f);
    }
    __syncthreads();
    fp W2 = m2W + e * 16 * 8; fp B2 = m2b + e * 8;
    for (int i = tid; i < 64 * 8; i += 256) {
        int g = i >> 3, c = i & 7;
        float a = B2[c];
        for (int f = 0; f < 16; ++f) a += A2[g * 16 + f] * W2[f * 8 + c];
        A3[i] = a > 0.f ? a : (__expf(a) - 1.f);
    }
    __syncthreads();
    fp W3 = m3W + e * 8;
    if (tid < 64) {
        int g = tid;
        float a = m3b[e];
        for (int j = 0; j < 8; ++j) a += A3[g * 8 + j] * W3[j];
        out[g * 6 + e] = a;  // preds [G,6] as float32
    }
}

__global__ __launch_bounds__(64) void loss_kernel(const float* __restrict__ preds, fp y,
                                                  float* __restrict__ out) {
    int lane = threadIdx.x;
    float lsum = 0.f;
    if (lane < 6) {
        float acc = 0.f;
        for (int g = 0; g < 64; ++g) {
            float d = preds[g * 6 + lane] - y[g * 6 + lane];
            acc += d * d;
        }
        lsum = sqrtf(acc / 64.f);
    }
#pragma unroll
    for (int off = 32; off; off >>= 1) lsum += __shfl_xor(lsum, off);
    if (lane == 0) out[384] = lsum;  // total_loss (float32) right after preds[64*6]
}

extern "C" void kernel_launch(void* const* d_in, const int* in_sizes, int n_in, void* d_out, int out_size,
                              void* d_ws, size_t ws_size, hipStream_t stream) {
    // Inputs follow setup_inputs() dict order: x, edge_index, edge_attr, batch, y, <30 weights>.
    // Float tensors are float32; OUTPUT dtype = float32 (validated round 5).
    bool dictOrder = (in_sizes[1] == 2 * N_EDGES);
    int iEI = dictOrder ? 1 : 33;
    int iEA = dictOrder ? 2 : 1;
    int iBT = dictOrder ? 3 : 34;
    int iY  = dictOrder ? 4 : 2;
    int w0  = dictOrder ? 5 : 3;  // first weight (Wq0)

    fp x = (fp)d_in[0];
    const int* ei = (const int*)d_in[iEI];
    fp eattr = (fp)d_in[iEA];
    const int* batch = (const int*)d_in[iBT];
    fp y = (fp)d_in[iY];
    fp Wq0 = (fp)d_in[w0 + 0], bq0 = (fp)d_in[w0 + 1], Wk0 = (fp)d_in[w0 + 2], bk0 = (fp)d_in[w0 + 3];
    fp Wv0 = (fp)d_in[w0 + 4], bv0 = (fp)d_in[w0 + 5], We0 = (fp)d_in[w0 + 6];
    fp Ws0 = (fp)d_in[w0 + 7], bs0 = (fp)d_in[w0 + 8];
    fp Wq = (fp)d_in[w0 + 9], bq = (fp)d_in[w0 + 10], Wk = (fp)d_in[w0 + 11], bk = (fp)d_in[w0 + 12];
    fp Wv = (fp)d_in[w0 + 13], bv = (fp)d_in[w0 + 14], Wel = (fp)d_in[w0 + 15];
    fp Ws = (fp)d_in[w0 + 16], bs = (fp)d_in[w0 + 17];
    fp g1W = (fp)d_in[w0 + 18], g1b = (fp)d_in[w0 + 19], g2W = (fp)d_in[w0 + 20], g2b = (fp)d_in[w0 + 21];
    fp m0W = (fp)d_in[w0 + 22], m0b = (fp)d_in[w0 + 23], m1W = (fp)d_in[w0 + 24], m1b = (fp)d_in[w0 + 25];
    fp m2W = (fp)d_in[w0 + 26], m2b = (fp)d_in[w0 + 27], m3W = (fp)d_in[w0 + 28], m3b = (fp)d_in[w0 + 29];

    const int* srcArr = ei;
    const int* dstArr = ei + N_EDGES;

    char* wsp = (char*)d_ws;
    auto alloc = [&](size_t bytes) -> void* {
        void* p = (void*)wsp;
        wsp += (bytes + 255) & ~(size_t)255;
        return p;
    };
    float* q = (float*)alloc((size_t)N_NODES * 64 * 4);
    float* kv = (float*)alloc((size_t)N_NODES * 128 * 4);  // k,v interleaved per node
    float* skb = (float*)alloc((size_t)N_NODES * 64 * 4);
    float* hbuf = (float*)alloc((size_t)N_NODES * 64 * 4);
    float* hmax = (float*)alloc((size_t)N_NODES * 64 * 4);
    float* gate = (float*)alloc((size_t)N_NODES * 4);
    float* pooled = (float*)alloc(64 * 64 * 4);
    int* row_ptr = (int*)alloc((N_NODES + 1) * 4);
    int* cursor = (int*)alloc((size_t)N_NODES * 4);
    int* csr_src = (int*)alloc((size_t)N_EDGES * 4);
    int* csr_eid = (int*)alloc((size_t)N_EDGES * 4);
    float* ea_csr = (float*)alloc((size_t)N_EDGES * 7 * 4);
    int* blksum = (int*)alloc(256 * 4);
    int* starts = (int*)alloc((N_GRAPHS + 1) * 4);
    (void)ws_size;
    (void)n_in;

    float* outF = (float*)d_out;  // [0..383] preds, [384] total_loss

    // ---- CSR build (by dst) ----
    hipMemsetAsync(cursor, 0, (size_t)N_NODES * 4, stream);
    count_kernel<<<(N_EDGES + 255) / 256, 256, 0, stream>>>(dstArr, cursor);
    scan1_kernel<<<NBLK, 512, 0, stream>>>(cursor, row_ptr, blksum);
    scan2_kernel<<<1, 256, 0, stream>>>(blksum);
    scan3_kernel<<<NBLK, 512, 0, stream>>>(row_ptr, blksum, cursor);
    scatter_kernel<<<(N_EDGES + 255) / 256, 256, 0, stream>>>(srcArr, dstArr, cursor, csr_src, csr_eid);
    permute_ea_kernel<<<(N_EDGES + 255) / 256, 256, 0, stream>>>(eattr, csr_eid, ea_csr);

    dim3 gg(N_NODES / 16, 4);
    // layer 0 (conv_first, 128 -> 64), ELU, init hmax
    gemm4_kernel<IN_CH><<<gg, 256, 0, stream>>>(x, Wq0, bq0, Wk0, bk0, Wv0, bv0, Ws0, bs0,
                                                q, 64, kv, 128, kv + 64, 128, skb, 64);
    node_kernel<<<N_NODES * 64 / 256, 256, 0, stream>>>(q, kv, skb, ea_csr, We0, row_ptr, csr_src,
                                                        hbuf, hmax, 1, 1);
    // layers 1..3 (64 -> 64); ELU except last; JK running max
    for (int i = 0; i < N_CONVS; ++i) {
        gemm4_kernel<DIM><<<gg, 256, 0, stream>>>(hbuf, Wq + i * 4096, bq + i * 64, Wk + i * 4096,
                                                  bk + i * 64, Wv + i * 4096, bv + i * 64, Ws + i * 4096,
                                                  bs + i * 64, q, 64, kv, 128, kv + 64, 128, skb, 64);
        node_kernel<<<N_NODES * 64 / 256, 256, 0, stream>>>(q, kv, skb, ea_csr, Wel + i * 448, row_ptr,
                                                            csr_src, hbuf, hmax,
                                                            (i < N_CONVS - 1) ? 1 : 0, 0);
    }
    // pooling head
    gate_kernel<<<N_NODES / 4, 256, 0, stream>>>(hmax, g1W, g1b, g2W, g2b, gate);
    starts_kernel<<<(N_NODES + 255) / 256, 256, 0, stream>>>(batch, starts);
    pool_kernel<<<N_GRAPHS, 256, 0, stream>>>(hmax, gate, starts, pooled);
    mlp_kernel<<<6, 256, 0, stream>>>(pooled, m0W, m0b, m1W, m1b, m2W, m2b, m3W, m3b, outF);
    loss_kernel<<<1, 64, 0, stream>>>(outF, y, outF);
}

// Round 8
// 1441.578 us; speedup vs baseline: 1.1851x; 1.0825x over previous
//
#include <hip/hip_runtime.h>
#include <math.h>

#define N_NODES 100000
#define N_EDGES 1600000
#define N_GRAPHS 64
#define IN_CH 128
#define DIM 64
#define N_CONVS 3
#define NBLK 196  // ceil(100000/512)

typedef const float* fp;
typedef unsigned int u32;

// ---------------- CSR build ----------------
__global__ __launch_bounds__(256) void count_kernel(const int* __restrict__ dst, int* __restrict__ cnt) {
    int j = blockIdx.x * 256 + threadIdx.x;
    if (j < N_EDGES) {
        int d = dst[j];
        if ((unsigned)d < N_NODES) atomicAdd(&cnt[d], 1);
    }
}

__global__ __launch_bounds__(512) void scan1_kernel(const int* __restrict__ cnt, int* __restrict__ rp,
                                                    int* __restrict__ blksum) {
    __shared__ int tmp[512];
    int t = threadIdx.x, i = blockIdx.x * 512 + t;
    int v0 = (i < N_NODES) ? cnt[i] : 0;
    tmp[t] = v0;
    __syncthreads();
    for (int off = 1; off < 512; off <<= 1) {
        int add = (t >= off) ? tmp[t - off] : 0;
        __syncthreads();
        tmp[t] += add;
        __syncthreads();
    }
    if (i < N_NODES) rp[i] = tmp[t] - v0;
    if (t == 511) blksum[blockIdx.x] = tmp[511];
}

__global__ __launch_bounds__(256) void scan2_kernel(int* __restrict__ blksum) {
    __shared__ int tmp[256];
    int t = threadIdx.x;
    int v0 = (t < NBLK) ? blksum[t] : 0;
    tmp[t] = v0;
    __syncthreads();
    for (int off = 1; off < 256; off <<= 1) {
        int add = (t >= off) ? tmp[t - off] : 0;
        __syncthreads();
        tmp[t] += add;
        __syncthreads();
    }
    if (t < NBLK) blksum[t] = tmp[t] - v0;
}

__global__ __launch_bounds__(512) void scan3_kernel(int* __restrict__ rp, const int* __restrict__ blksum,
                                                    int* __restrict__ cursor) {
    int t = threadIdx.x, i = blockIdx.x * 512 + t;
    if (i < N_NODES) {
        int v = rp[i] + blksum[blockIdx.x];
        rp[i] = v;
        cursor[i] = v;
    }
    if (i == 0) rp[N_NODES] = N_EDGES;
}

__global__ __launch_bounds__(256) void scatter_kernel(const int* __restrict__ src, const int* __restrict__ dst,
                                                      int* __restrict__ cursor, int* __restrict__ csr_src,
                                                      int* __restrict__ csr_eid) {
    int j = blockIdx.x * 256 + threadIdx.x;
    if (j < N_EDGES) {
        int d = dst[j];
        if ((unsigned)d >= N_NODES) return;
        int pos = atomicAdd(&cursor[d], 1);
        if ((unsigned)pos < N_EDGES) {
            int s = src[j];
            csr_src[pos] = ((unsigned)s < N_NODES) ? s : 0;
            csr_eid[pos] = j;
        }
    }
}

// permute edge_attr into CSR order (reused by all 4 conv layers)
__global__ __launch_bounds__(256) void permute_ea_kernel(fp ea, const int* __restrict__ csr_eid,
                                                         float* __restrict__ ea_csr) {
    int p = blockIdx.x * 256 + threadIdx.x;
    if (p < N_EDGES) {
        int eid = csr_eid[p];
        size_t sb = (size_t)eid * 7, db = (size_t)p * 7;
#pragma unroll
        for (int c = 0; c < 7; ++c) ea_csr[db + c] = ea[sb + c];
    }
}

// ---------------- bf16 pack (RNE) ----------------
__device__ inline u32 pack_kv(float k, float v) {
    u32 uk = __float_as_uint(k), uv = __float_as_uint(v);
    u32 lk = (uk + 0x7fffu + ((uk >> 16) & 1u)) >> 16;
    u32 lv = (uv + 0x7fffu + ((uv >> 16) & 1u)) >> 16;
    return lk | (lv << 16);
}

// ---------------- node-feature GEMMs: y=0 -> q (prescaled 1/8), y=1 -> skip, y=2 -> packed kv ----------------
template <int IN>
__global__ __launch_bounds__(256) void gemm_kernel(
    const float* __restrict__ h,
    fp Wq, fp bq, fp Wk, fp bk, fp Wv, fp bv, fp Ws, fp bs,
    float* __restrict__ q, u32* __restrict__ kvp, float* __restrict__ skb) {
    __shared__ float hs[16][IN];
    int mat = blockIdx.y;
    int row0 = blockIdx.x * 16;  // N_NODES % 16 == 0
    for (int idx = threadIdx.x; idx < 16 * IN; idx += 256) {
        int r = idx / IN, c = idx - r * IN;
        hs[r][c] = h[(size_t)(row0 + r) * IN + c];
    }
    __syncthreads();
    int c = threadIdx.x & 63, rg = threadIdx.x >> 6;
    if (mat == 2) {
        float k0 = 0, k1 = 0, k2 = 0, k3 = 0, v0 = 0, v1 = 0, v2 = 0, v3 = 0;
        for (int kk = 0; kk < IN; ++kk) {
            float wk = Wk[kk * 64 + c], wv = Wv[kk * 64 + c];
            float h0 = hs[rg][kk], h1 = hs[rg + 4][kk], h2 = hs[rg + 8][kk], h3 = hs[rg + 12][kk];
            k0 += h0 * wk; k1 += h1 * wk; k2 += h2 * wk; k3 += h3 * wk;
            v0 += h0 * wv; v1 += h1 * wv; v2 += h2 * wv; v3 += h3 * wv;
        }
        float bkc = bk[c], bvc = bv[c];
        kvp[(size_t)(row0 + rg) * 64 + c]      = pack_kv(k0 + bkc, v0 + bvc);
        kvp[(size_t)(row0 + rg + 4) * 64 + c]  = pack_kv(k1 + bkc, v1 + bvc);
        kvp[(size_t)(row0 + rg + 8) * 64 + c]  = pack_kv(k2 + bkc, v2 + bvc);
        kvp[(size_t)(row0 + rg + 12) * 64 + c] = pack_kv(k3 + bkc, v3 + bvc);
    } else {
        fp W = mat == 0 ? Wq : Ws;
        fp B = mat == 0 ? bq : bs;
        float* O = mat == 0 ? q : skb;
        float scale = mat == 0 ? 0.125f : 1.f;
        float a0 = 0, a1 = 0, a2 = 0, a3 = 0;
        for (int kk = 0; kk < IN; ++kk) {
            float wv = W[kk * 64 + c];
            a0 += hs[rg][kk] * wv;
            a1 += hs[rg + 4][kk] * wv;
            a2 += hs[rg + 8][kk] * wv;
            a3 += hs[rg + 12][kk] * wv;
        }
        float bb = B[c];
        O[(size_t)(row0 + rg) * 64 + c] = (a0 + bb) * scale;
        O[(size_t)(row0 + rg + 4) * 64 + c] = (a1 + bb) * scale;
        O[(size_t)(row0 + rg + 8) * 64 + c] = (a2 + bb) * scale;
        O[(size_t)(row0 + rg + 12) * 64 + c] = (a3 + bb) * scale;
    }
}

// qwe[n][c] = sum_f qs[n][f] * We[c][f]  (qs already prescaled by 1/8)
__global__ __launch_bounds__(256) void qwe_kernel(const float* __restrict__ qs, fp We,
                                                  float* __restrict__ qwe) {
    int n = (blockIdx.x * 256 + threadIdx.x) >> 6;
    int lane = threadIdx.x & 63;
    float qf = qs[(size_t)n * 64 + lane];
#pragma unroll
    for (int c = 0; c < 7; ++c) {
        float t = qf * We[c * 64 + lane];
#pragma unroll
        for (int off = 32; off; off >>= 1) t += __shfl_xor(t, off);
        if (lane == 0) qwe[(size_t)n * 7 + c] = t;
    }
}

// ---------------- per-node edge aggregation: 16-lane groups, packed bf16 kv, no-max softmax ----------------
__global__ __launch_bounds__(256) void node_kernel(
    const float* __restrict__ qs, const u32* __restrict__ kvp, const float* __restrict__ skb,
    const float* __restrict__ qwe, const float* __restrict__ ea_csr, fp We,
    const int* __restrict__ row_ptr, const int* __restrict__ csr_src,
    float* __restrict__ h_out, float* __restrict__ hmax, int act, int initmax) {
    int tid = threadIdx.x;
    int lane = tid & 63;
    int g = lane >> 4, fl = lane & 15;
    int gbase = g << 4;
    int n = blockIdx.x * 16 + (tid >> 6) * 4 + g;
    int f0 = fl * 4;
    float4 q4 = *reinterpret_cast<const float4*>(&qs[(size_t)n * 64 + f0]);
    float qw[7];
#pragma unroll
    for (int c = 0; c < 7; ++c) qw[c] = qwe[(size_t)n * 7 + c];
    int beg = row_ptr[n], end = row_ptr[n + 1];
    float s = 0.f;
    float ax = 0.f, ay = 0.f, az = 0.f, aw = 0.f;
    float r[7];
#pragma unroll
    for (int c = 0; c < 7; ++c) r[c] = 0.f;

    for (int p = beg; p < end; p += 4) {
        int svi = p + (fl & 3);
        svi = svi < end ? svi : end - 1;
        int sv = csr_src[svi];
#pragma unroll
        for (int j = 0; j < 4; ++j) {
            int pj = p + j;
            int pc = pj < end ? pj : end - 1;
            int sn = __shfl(sv, gbase + j);
            uint4 kv4 = *reinterpret_cast<const uint4*>(&kvp[(size_t)sn * 64 + f0]);
            const float* eb = ea_csr + (size_t)pc * 7;
            float e[7];
#pragma unroll
            for (int c = 0; c < 7; ++c) e[c] = eb[c];
            float al = qw[0] * e[0];
#pragma unroll
            for (int c = 1; c < 7; ++c) al += qw[c] * e[c];
            float kf0 = __uint_as_float(kv4.x << 16), vf0 = __uint_as_float(kv4.x & 0xffff0000u);
            float kf1 = __uint_as_float(kv4.y << 16), vf1 = __uint_as_float(kv4.y & 0xffff0000u);
            float kf2 = __uint_as_float(kv4.z << 16), vf2 = __uint_as_float(kv4.z & 0xffff0000u);
            float kf3 = __uint_as_float(kv4.w << 16), vf3 = __uint_as_float(kv4.w & 0xffff0000u);
            float d = q4.x * kf0 + q4.y * kf1 + q4.z * kf2 + q4.w * kf3;
            d += __shfl_xor(d, 1);
            d += __shfl_xor(d, 2);
            d += __shfl_xor(d, 4);
            d += __shfl_xor(d, 8);
            float pe = (pj < end) ? __expf(al + d) : 0.f;
            s += pe;
            ax += pe * vf0; ay += pe * vf1; az += pe * vf2; aw += pe * vf3;
#pragma unroll
            for (int c = 0; c < 7; ++c) r[c] += pe * e[c];
        }
    }
    float inv = 1.f / (s + 1e-16f);
    float o0 = ax, o1 = ay, o2 = az, o3 = aw;
#pragma unroll
    for (int c = 0; c < 7; ++c) {
        o0 += We[c * 64 + f0 + 0] * r[c];
        o1 += We[c * 64 + f0 + 1] * r[c];
        o2 += We[c * 64 + f0 + 2] * r[c];
        o3 += We[c * 64 + f0 + 3] * r[c];
    }
    float4 sk4 = *reinterpret_cast<const float4*>(&skb[(size_t)n * 64 + f0]);
    float4 res;
    res.x = o0 * inv + sk4.x;
    res.y = o1 * inv + sk4.y;
    res.z = o2 * inv + sk4.z;
    res.w = o3 * inv + sk4.w;
    if (act) {
        res.x = res.x > 0.f ? res.x : (__expf(res.x) - 1.f);
        res.y = res.y > 0.f ? res.y : (__expf(res.y) - 1.f);
        res.z = res.z > 0.f ? res.z : (__expf(res.z) - 1.f);
        res.w = res.w > 0.f ? res.w : (__expf(res.w) - 1.f);
    }
    *reinterpret_cast<float4*>(&h_out[(size_t)n * 64 + f0]) = res;
    if (initmax) {
        *reinterpret_cast<float4*>(&hmax[(size_t)n * 64 + f0]) = res;
    } else {
        float4 hm = *reinterpret_cast<const float4*>(&hmax[(size_t)n * 64 + f0]);
        hm.x = fmaxf(hm.x, res.x);
        hm.y = fmaxf(hm.y, res.y);
        hm.z = fmaxf(hm.z, res.z);
        hm.w = fmaxf(hm.w, res.w);
        *reinterpret_cast<float4*>(&hmax[(size_t)n * 64 + f0]) = hm;
    }
}

// ---------------- gate MLP per node ----------------
__global__ __launch_bounds__(256) void gate_kernel(const float* __restrict__ h, fp g1W, fp g1b, fp g2W,
                                                   fp g2b, float* __restrict__ gate) {
    __shared__ float hs[4][64];
    int w = threadIdx.x >> 6, lane = threadIdx.x & 63;
    int n = blockIdx.x * 4 + w;
    hs[w][lane] = h[(size_t)n * 64 + lane];
    __syncthreads();
    float a = 0.f;
    for (int f = 0; f < 64; ++f) a += hs[w][f] * g1W[f * 64 + lane];
    a = fmaxf(a + g1b[lane], 0.f);
    float val = a * g2W[lane];
#pragma unroll
    for (int off = 32; off; off >>= 1) val += __shfl_xor(val, off);
    if (lane == 0) gate[n] = val + g2b[0];
}

// ---------------- graph boundaries (batch sorted) ----------------
__global__ __launch_bounds__(256) void starts_kernel(const int* __restrict__ batch, int* __restrict__ starts) {
    int i = blockIdx.x * 256 + threadIdx.x;
    if (i >= N_NODES) return;
    if (i == 0) {
        int b = batch[0];
        for (int g = 0; g <= b && g <= N_GRAPHS; ++g) starts[g] = 0;
    } else {
        int b0 = batch[i - 1], b1 = batch[i];
        for (int g = b0 + 1; g <= b1 && g <= N_GRAPHS; ++g) starts[g] = i;
    }
    if (i == N_NODES - 1) {
        int b = batch[i];
        for (int g = b + 1; g <= N_GRAPHS; ++g) starts[g] = N_NODES;
    }
}

// ---------------- gated softmax pooling, one block per graph ----------------
__global__ __launch_bounds__(256) void pool_kernel(const float* __restrict__ h, const float* __restrict__ gate,
                                                   const int* __restrict__ starts, float* __restrict__ pooled) {
    int g = blockIdx.x;
    int beg = starts[g], end = starts[g + 1];
    int tid = threadIdx.x, lane = tid & 63, w = tid >> 6;
    __shared__ float red[4];
    __shared__ float accs[4][64];
    float m = -INFINITY;
    for (int i = beg + tid; i < end; i += 256) m = fmaxf(m, gate[i]);
#pragma unroll
    for (int off = 32; off; off >>= 1) m = fmaxf(m, __shfl_xor(m, off));
    if (lane == 0) red[w] = m;
    __syncthreads();
    m = fmaxf(fmaxf(red[0], red[1]), fmaxf(red[2], red[3]));
    __syncthreads();
    float s = 0.f;
    for (int i = beg + tid; i < end; i += 256) s += __expf(gate[i] - m);
#pragma unroll
    for (int off = 32; off; off >>= 1) s += __shfl_xor(s, off);
    if (lane == 0) red[w] = s;
    __syncthreads();
    s = red[0] + red[1] + red[2] + red[3] + 1e-16f;
    float acc = 0.f;
    for (int i = beg + w; i < end; i += 4) {
        float p = __expf(gate[i] - m);
        acc += p * h[(size_t)i * 64 + lane];
    }
    accs[w][lane] = acc;
    __syncthreads();
    if (w == 0) pooled[g * 64 + lane] = (accs[0][lane] + accs[1][lane] + accs[2][lane] + accs[3][lane]) / s;
}

// ---------------- 6-expert MLP head (f32 output) ----------------
__global__ __launch_bounds__(256) void mlp_kernel(const float* __restrict__ pooled, fp m0W, fp m0b, fp m1W,
                                                  fp m1b, fp m2W, fp m2b, fp m3W, fp m3b,
                                                  float* __restrict__ out) {
    int e = blockIdx.x, tid = threadIdx.x;
    __shared__ float P[64 * 64];
    __shared__ float A1[64 * 32];
    __shared__ float A2[64 * 16];
    __shared__ float A3[64 * 8];
    for (int i = tid; i < 64 * 64; i += 256) P[i] = pooled[i];
    __syncthreads();
    fp W0 = m0W + e * 64 * 32; fp B0 = m0b + e * 32;
    for (int i = tid; i < 64 * 32; i += 256) {
        int g = i >> 5, c = i & 31;
        float a = B0[c];
        for (int f = 0; f < 64; ++f) a += P[g * 64 + f] * W0[f * 32 + c];
        A1[i] = a > 0.f ? a : (__expf(a) - 1.f);
    }
    __syncthreads();
    fp W1 = m1W + e * 32 * 16; fp B1 = m1b + e * 16;
    for (int i = tid; i < 64 * 16; i += 256) {
        int g = i >> 4, c = i & 15;
        float a = B1[c];
        for (int f = 0; f < 32; ++f) a += A1[g * 32 + f] * W1[f * 16 + c];
        A2[i] = a > 0.f ? a : (__expf(a) - 1.f);
    }
    __syncthreads();
    fp W2 = m2W + e * 16 * 8; fp B2 = m2b + e * 8;
    for (int i = tid; i < 64 * 8; i += 256) {
        int g = i >> 3, c = i & 7;
        float a = B2[c];
        for (int f = 0; f < 16; ++f) a += A2[g * 16 + f] * W2[f * 8 + c];
        A3[i] = a > 0.f ? a : (__expf(a) - 1.f);
    }
    __syncthreads();
    fp W3 = m3W + e * 8;
    if (tid < 64) {
        int g = tid;
        float a = m3b[e];
        for (int j = 0; j < 8; ++j) a += A3[g * 8 + j] * W3[j];
        out[g * 6 + e] = a;
    }
}

__global__ __launch_bounds__(64) void loss_kernel(const float* __restrict__ preds, fp y,
                                                  float* __restrict__ out) {
    int lane = threadIdx.x;
    float lsum = 0.f;
    if (lane < 6) {
        float acc = 0.f;
        for (int g = 0; g < 64; ++g) {
            float d = preds[g * 6 + lane] - y[g * 6 + lane];
            acc += d * d;
        }
        lsum = sqrtf(acc / 64.f);
    }
#pragma unroll
    for (int off = 32; off; off >>= 1) lsum += __shfl_xor(lsum, off);
    if (lane == 0) out[384] = lsum;
}

extern "C" void kernel_launch(void* const* d_in, const int* in_sizes, int n_in, void* d_out, int out_size,
                              void* d_ws, size_t ws_size, hipStream_t stream) {
    bool dictOrder = (in_sizes[1] == 2 * N_EDGES);
    int iEI = dictOrder ? 1 : 33;
    int iEA = dictOrder ? 2 : 1;
    int iBT = dictOrder ? 3 : 34;
    int iY  = dictOrder ? 4 : 2;
    int w0  = dictOrder ? 5 : 3;

    fp x = (fp)d_in[0];
    const int* ei = (const int*)d_in[iEI];
    fp eattr = (fp)d_in[iEA];
    const int* batch = (const int*)d_in[iBT];
    fp y = (fp)d_in[iY];
    fp Wq0 = (fp)d_in[w0 + 0], bq0 = (fp)d_in[w0 + 1], Wk0 = (fp)d_in[w0 + 2], bk0 = (fp)d_in[w0 + 3];
    fp Wv0 = (fp)d_in[w0 + 4], bv0 = (fp)d_in[w0 + 5], We0 = (fp)d_in[w0 + 6];
    fp Ws0 = (fp)d_in[w0 + 7], bs0 = (fp)d_in[w0 + 8];
    fp Wq = (fp)d_in[w0 + 9], bq = (fp)d_in[w0 + 10], Wk = (fp)d_in[w0 + 11], bk = (fp)d_in[w0 + 12];
    fp Wv = (fp)d_in[w0 + 13], bv = (fp)d_in[w0 + 14], Wel = (fp)d_in[w0 + 15];
    fp Ws = (fp)d_in[w0 + 16], bs = (fp)d_in[w0 + 17];
    fp g1W = (fp)d_in[w0 + 18], g1b = (fp)d_in[w0 + 19], g2W = (fp)d_in[w0 + 20], g2b = (fp)d_in[w0 + 21];
    fp m0W = (fp)d_in[w0 + 22], m0b = (fp)d_in[w0 + 23], m1W = (fp)d_in[w0 + 24], m1b = (fp)d_in[w0 + 25];
    fp m2W = (fp)d_in[w0 + 26], m2b = (fp)d_in[w0 + 27], m3W = (fp)d_in[w0 + 28], m3b = (fp)d_in[w0 + 29];

    const int* srcArr = ei;
    const int* dstArr = ei + N_EDGES;

    char* wsp = (char*)d_ws;
    auto alloc = [&](size_t bytes) -> void* {
        void* p = (void*)wsp;
        wsp += (bytes + 255) & ~(size_t)255;
        return p;
    };
    float* q = (float*)alloc((size_t)N_NODES * 64 * 4);        // prescaled by 1/8
    u32* kvp = (u32*)alloc((size_t)N_NODES * 64 * 4);          // packed bf16 (k | v<<16)
    float* skb = (float*)alloc((size_t)N_NODES * 64 * 4);
    float* hbuf = (float*)alloc((size_t)N_NODES * 64 * 4);
    float* hmax = (float*)alloc((size_t)N_NODES * 64 * 4);
    float* qwe = (float*)alloc((size_t)N_NODES * 7 * 4);
    float* gate = (float*)alloc((size_t)N_NODES * 4);
    float* pooled = (float*)alloc(64 * 64 * 4);
    int* row_ptr = (int*)alloc((N_NODES + 1) * 4);
    int* cursor = (int*)alloc((size_t)N_NODES * 4);
    int* csr_src = (int*)alloc((size_t)N_EDGES * 4);
    int* csr_eid = (int*)alloc((size_t)N_EDGES * 4);
    float* ea_csr = (float*)alloc((size_t)N_EDGES * 7 * 4);
    int* blksum = (int*)alloc(256 * 4);
    int* starts = (int*)alloc((N_GRAPHS + 1) * 4);
    (void)ws_size;
    (void)n_in;

    float* outF = (float*)d_out;  // [0..383] preds, [384] total_loss

    // ---- CSR build (by dst) ----
    hipMemsetAsync(cursor, 0, (size_t)N_NODES * 4, stream);
    count_kernel<<<(N_EDGES + 255) / 256, 256, 0, stream>>>(dstArr, cursor);
    scan1_kernel<<<NBLK, 512, 0, stream>>>(cursor, row_ptr, blksum);
    scan2_kernel<<<1, 256, 0, stream>>>(blksum);
    scan3_kernel<<<NBLK, 512, 0, stream>>>(row_ptr, blksum, cursor);
    scatter_kernel<<<(N_EDGES + 255) / 256, 256, 0, stream>>>(srcArr, dstArr, cursor, csr_src, csr_eid);
    permute_ea_kernel<<<(N_EDGES + 255) / 256, 256, 0, stream>>>(eattr, csr_eid, ea_csr);

    dim3 gg(N_NODES / 16, 3);
    int nodeGrid = N_NODES / 16;  // 16 nodes per 256-thread block (16 lanes/node)
    // layer 0 (conv_first, 128 -> 64), ELU, init hmax
    gemm_kernel<IN_CH><<<gg, 256, 0, stream>>>(x, Wq0, bq0, Wk0, bk0, Wv0, bv0, Ws0, bs0, q, kvp, skb);
    qwe_kernel<<<N_NODES * 64 / 256, 256, 0, stream>>>(q, We0, qwe);
    node_kernel<<<nodeGrid, 256, 0, stream>>>(q, kvp, skb, qwe, ea_csr, We0, row_ptr, csr_src,
                                              hbuf, hmax, 1, 1);
    // layers 1..3 (64 -> 64); ELU except last; JK running max
    for (int i = 0; i < N_CONVS; ++i) {
        gemm_kernel<DIM><<<gg, 256, 0, stream>>>(hbuf, Wq + i * 4096, bq + i * 64, Wk + i * 4096,
                                                 bk + i * 64, Wv + i * 4096, bv + i * 64, Ws + i * 4096,
                                                 bs + i * 64, q, kvp, skb);
        qwe_kernel<<<N_NODES * 64 / 256, 256, 0, stream>>>(q, Wel + i * 448, qwe);
        node_kernel<<<nodeGrid, 256, 0, stream>>>(q, kvp, skb, qwe, ea_csr, Wel + i * 448, row_ptr,
                                                  csr_src, hbuf, hmax, (i < N_CONVS - 1) ? 1 : 0, 0);
    }
    // pooling head
    gate_kernel<<<N_NODES / 4, 256, 0, stream>>>(hmax, g1W, g1b, g2W, g2b, gate);
    starts_kernel<<<(N_NODES + 255) / 256, 256, 0, stream>>>(batch, starts);
    pool_kernel<<<N_GRAPHS, 256, 0, stream>>>(hmax, gate, starts, pooled);
    mlp_kernel<<<6, 256, 0, stream>>>(pooled, m0W, m0b, m1W, m1b, m2W, m2b, m3W, m3b, outF);
    loss_kernel<<<1, 64, 0, stream>>>(outF, y, outF);
}

// Round 9
// 1218.816 us; speedup vs baseline: 1.4017x; 1.1828x over previous
//
#include <hip/hip_runtime.h>
#include <math.h>

#define N_NODES 100000
#define N_EDGES 1600000
#define N_GRAPHS 64
#define IN_CH 128
#define DIM 64
#define N_CONVS 3
#define NBLK 196  // ceil(100000/512)

typedef const float* fp;
typedef unsigned int u32;
typedef unsigned short u16;
typedef __attribute__((ext_vector_type(8))) short short8v;
typedef __attribute__((ext_vector_type(4))) float f32x4;

__device__ inline u16 rne_bf16(float f) {
    u32 u = __float_as_uint(f);
    return (u16)((u + 0x7fffu + ((u >> 16) & 1u)) >> 16);
}

// ---------------- CSR build ----------------
__global__ __launch_bounds__(256) void count_kernel(const int* __restrict__ dst, int* __restrict__ cnt) {
    int j = blockIdx.x * 256 + threadIdx.x;
    if (j < N_EDGES) {
        int d = dst[j];
        if ((unsigned)d < N_NODES) atomicAdd(&cnt[d], 1);
    }
}

__global__ __launch_bounds__(512) void scan1_kernel(const int* __restrict__ cnt, int* __restrict__ rp,
                                                    int* __restrict__ blksum) {
    __shared__ int tmp[512];
    int t = threadIdx.x, i = blockIdx.x * 512 + t;
    int v0 = (i < N_NODES) ? cnt[i] : 0;
    tmp[t] = v0;
    __syncthreads();
    for (int off = 1; off < 512; off <<= 1) {
        int add = (t >= off) ? tmp[t - off] : 0;
        __syncthreads();
        tmp[t] += add;
        __syncthreads();
    }
    if (i < N_NODES) rp[i] = tmp[t] - v0;
    if (t == 511) blksum[blockIdx.x] = tmp[511];
}

__global__ __launch_bounds__(256) void scan2_kernel(int* __restrict__ blksum) {
    __shared__ int tmp[256];
    int t = threadIdx.x;
    int v0 = (t < NBLK) ? blksum[t] : 0;
    tmp[t] = v0;
    __syncthreads();
    for (int off = 1; off < 256; off <<= 1) {
        int add = (t >= off) ? tmp[t - off] : 0;
        __syncthreads();
        tmp[t] += add;
        __syncthreads();
    }
    if (t < NBLK) blksum[t] = tmp[t] - v0;
}

__global__ __launch_bounds__(512) void scan3_kernel(int* __restrict__ rp, const int* __restrict__ blksum,
                                                    int* __restrict__ cursor) {
    int t = threadIdx.x, i = blockIdx.x * 512 + t;
    if (i < N_NODES) {
        int v = rp[i] + blksum[blockIdx.x];
        rp[i] = v;
        cursor[i] = v;
    }
    if (i == 0) rp[N_NODES] = N_EDGES;
}

__global__ __launch_bounds__(256) void scatter_kernel(const int* __restrict__ src, const int* __restrict__ dst,
                                                      int* __restrict__ cursor, int* __restrict__ csr_src,
                                                      int* __restrict__ csr_eid) {
    int j = blockIdx.x * 256 + threadIdx.x;
    if (j < N_EDGES) {
        int d = dst[j];
        if ((unsigned)d >= N_NODES) return;
        int pos = atomicAdd(&cursor[d], 1);
        if ((unsigned)pos < N_EDGES) {
            int s = src[j];
            csr_src[pos] = ((unsigned)s < N_NODES) ? s : 0;
            csr_eid[pos] = j;
        }
    }
}

__global__ __launch_bounds__(256) void permute_ea_kernel(fp ea, const int* __restrict__ csr_eid,
                                                         float* __restrict__ ea_csr) {
    int p = blockIdx.x * 256 + threadIdx.x;
    if (p < N_EDGES) {
        int eid = csr_eid[p];
        size_t sb = (size_t)eid * 7, db = (size_t)p * 7;
#pragma unroll
        for (int c = 0; c < 7; ++c) ea_csr[db + c] = ea[sb + c];
    }
}

// ---------------- x -> bf16 ----------------
__global__ __launch_bounds__(256) void cvt_bf16_kernel(const float* __restrict__ in, u16* __restrict__ out,
                                                       int n4) {
    int i = blockIdx.x * 256 + threadIdx.x;
    if (i < n4) {
        float4 v = reinterpret_cast<const float4*>(in)[i];
        ushort4 o;
        o.x = rne_bf16(v.x); o.y = rne_bf16(v.y); o.z = rne_bf16(v.z); o.w = rne_bf16(v.w);
        reinterpret_cast<ushort4*>(out)[i] = o;
    }
}

// ---------------- pack W (q|k|v|s -> K x 256) into MFMA B-fragment order ----------------
// frag(tk, gtn): lane l, elem j -> B[k = tk*32 + (l>>4)*8 + j][n = gtn*16 + (l&15)]
__global__ __launch_bounds__(256) void packW_kernel(fp Wq, fp Wk, fp Wv, fp Ws, u16* __restrict__ Bp,
                                                    int K) {
    int total = (K / 32) * 16 * 512;
    int tid = blockIdx.x * 256 + threadIdx.x;
    if (tid >= total) return;
    int j = tid & 7, l = (tid >> 3) & 63, fragid = tid >> 9;
    int tk = fragid >> 4, gtn = fragid & 15;
    int k = tk * 32 + ((l >> 4) << 3) + j;
    int n = (gtn << 4) + (l & 15);
    int mat = n >> 6, cn = n & 63;
    fp W = mat == 0 ? Wq : mat == 1 ? Wk : mat == 2 ? Wv : Ws;
    Bp[tid] = rne_bf16(W[k * 64 + cn]);
}

// ---------------- fused MFMA GEMM: [M x K] @ [K x 256] -> q(f32*1/8) | k(bf16) | v(bf16) | skip(f32) ----------------
template <int K>
__global__ __launch_bounds__(256) void gemm_mfma_kernel(
    const u16* __restrict__ A, const u16* __restrict__ Bp,
    fp bq, fp bk, fp bv, fp bs,
    float* __restrict__ q, u16* __restrict__ kb, u16* __restrict__ vb, float* __restrict__ skb) {
    constexpr int NTK = K / 32;
    int wave = threadIdx.x >> 6;  // 0:q 1:k 2:v 3:skip
    int l = threadIdx.x & 63;
    int lr = l & 15, lg = l >> 4;
    int row0 = blockIdx.x * 32;
    short8v a[2][NTK];
#pragma unroll
    for (int mi = 0; mi < 2; ++mi)
#pragma unroll
        for (int tk = 0; tk < NTK; ++tk)
            a[mi][tk] = *reinterpret_cast<const short8v*>(
                &A[(size_t)(row0 + mi * 16 + lr) * K + tk * 32 + lg * 8]);
    f32x4 c[2][4] = {};
#pragma unroll
    for (int tn = 0; tn < 4; ++tn) {
        int gtn = wave * 4 + tn;
#pragma unroll
        for (int tk = 0; tk < NTK; ++tk) {
            short8v b = *reinterpret_cast<const short8v*>(&Bp[((size_t)(tk * 16 + gtn) * 64 + l) * 8]);
            c[0][tn] = __builtin_amdgcn_mfma_f32_16x16x32_bf16(a[0][tk], b, c[0][tn], 0, 0, 0);
            c[1][tn] = __builtin_amdgcn_mfma_f32_16x16x32_bf16(a[1][tk], b, c[1][tn], 0, 0, 0);
        }
    }
    fp bias = wave == 0 ? bq : wave == 1 ? bk : wave == 2 ? bv : bs;
#pragma unroll
    for (int tn = 0; tn < 4; ++tn) {
        int cl = tn * 16 + lr;  // 0..63 within this wave's matrix
        float bb = bias[cl];
#pragma unroll
        for (int mi = 0; mi < 2; ++mi)
#pragma unroll
            for (int r = 0; r < 4; ++r) {
                size_t row = row0 + mi * 16 + lg * 4 + r;
                float val = c[mi][tn][r] + bb;
                if (wave == 0) q[row * 64 + cl] = val * 0.125f;
                else if (wave == 3) skb[row * 64 + cl] = val;
                else if (wave == 1) kb[row * 64 + cl] = rne_bf16(val);
                else vb[row * 64 + cl] = rne_bf16(val);
            }
    }
}

// qwe[n][c] = sum_f qs[n][f] * We[c][f]  (qs prescaled by 1/8)
__global__ __launch_bounds__(256) void qwe_kernel(const float* __restrict__ qs, fp We,
                                                  float* __restrict__ qwe) {
    int n = (blockIdx.x * 256 + threadIdx.x) >> 6;
    int lane = threadIdx.x & 63;
    float qf = qs[(size_t)n * 64 + lane];
#pragma unroll
    for (int c = 0; c < 7; ++c) {
        float t = qf * We[c * 64 + lane];
#pragma unroll
        for (int off = 32; off; off >>= 1) t += __shfl_xor(t, off);
        if (lane == 0) qwe[(size_t)n * 7 + c] = t;
    }
}

// ---------------- per-node edge aggregation: 16-lane groups, bf16 k/v, no-max softmax ----------------
__global__ __launch_bounds__(256) void node_kernel(
    const float* __restrict__ qs, const u16* __restrict__ kb, const u16* __restrict__ vb,
    const float* __restrict__ skb, const float* __restrict__ qwe, const float* __restrict__ ea_csr, fp We,
    const int* __restrict__ row_ptr, const int* __restrict__ csr_src,
    u16* __restrict__ hb, float* __restrict__ hmax, int act, int initmax) {
    int tid = threadIdx.x;
    int lane = tid & 63;
    int g = lane >> 4, fl = lane & 15;
    int gbase = g << 4;
    int n = blockIdx.x * 16 + (tid >> 6) * 4 + g;
    int f0 = fl * 4;
    float4 q4 = *reinterpret_cast<const float4*>(&qs[(size_t)n * 64 + f0]);
    float qw[7];
#pragma unroll
    for (int c = 0; c < 7; ++c) qw[c] = qwe[(size_t)n * 7 + c];
    int beg = row_ptr[n], end = row_ptr[n + 1];
    float s = 0.f;
    float ax = 0.f, ay = 0.f, az = 0.f, aw = 0.f;
    float r[7];
#pragma unroll
    for (int c = 0; c < 7; ++c) r[c] = 0.f;

    for (int p = beg; p < end; p += 4) {
        int svi = p + (fl & 3);
        svi = svi < end ? svi : end - 1;
        int sv = csr_src[svi];
#pragma unroll
        for (int j = 0; j < 4; ++j) {
            int pj = p + j;
            int pc = pj < end ? pj : end - 1;
            int sn = __shfl(sv, gbase + j);
            uint2 k2 = *reinterpret_cast<const uint2*>(&kb[(size_t)sn * 64 + f0]);
            uint2 v2 = *reinterpret_cast<const uint2*>(&vb[(size_t)sn * 64 + f0]);
            const float* eb = ea_csr + (size_t)pc * 7;
            float e[7];
#pragma unroll
            for (int c = 0; c < 7; ++c) e[c] = eb[c];
            float al = qw[0] * e[0];
#pragma unroll
            for (int c = 1; c < 7; ++c) al += qw[c] * e[c];
            float kf0 = __uint_as_float(k2.x << 16), kf1 = __uint_as_float(k2.x & 0xffff0000u);
            float kf2 = __uint_as_float(k2.y << 16), kf3 = __uint_as_float(k2.y & 0xffff0000u);
            float vf0 = __uint_as_float(v2.x << 16), vf1 = __uint_as_float(v2.x & 0xffff0000u);
            float vf2 = __uint_as_float(v2.y << 16), vf3 = __uint_as_float(v2.y & 0xffff0000u);
            float d = q4.x * kf0 + q4.y * kf1 + q4.z * kf2 + q4.w * kf3;
            d += __shfl_xor(d, 1);
            d += __shfl_xor(d, 2);
            d += __shfl_xor(d, 4);
            d += __shfl_xor(d, 8);
            float pe = (pj < end) ? __expf(al + d) : 0.f;
            s += pe;
            ax += pe * vf0; ay += pe * vf1; az += pe * vf2; aw += pe * vf3;
#pragma unroll
            for (int c = 0; c < 7; ++c) r[c] += pe * e[c];
        }
    }
    float inv = 1.f / (s + 1e-16f);
    float o0 = ax, o1 = ay, o2 = az, o3 = aw;
#pragma unroll
    for (int c = 0; c < 7; ++c) {
        o0 += We[c * 64 + f0 + 0] * r[c];
        o1 += We[c * 64 + f0 + 1] * r[c];
        o2 += We[c * 64 + f0 + 2] * r[c];
        o3 += We[c * 64 + f0 + 3] * r[c];
    }
    float4 sk4 = *reinterpret_cast<const float4*>(&skb[(size_t)n * 64 + f0]);
    float4 res;
    res.x = o0 * inv + sk4.x;
    res.y = o1 * inv + sk4.y;
    res.z = o2 * inv + sk4.z;
    res.w = o3 * inv + sk4.w;
    if (act) {
        res.x = res.x > 0.f ? res.x : (__expf(res.x) - 1.f);
        res.y = res.y > 0.f ? res.y : (__expf(res.y) - 1.f);
        res.z = res.z > 0.f ? res.z : (__expf(res.z) - 1.f);
        res.w = res.w > 0.f ? res.w : (__expf(res.w) - 1.f);
    }
    ushort4 hb4;
    hb4.x = rne_bf16(res.x); hb4.y = rne_bf16(res.y); hb4.z = rne_bf16(res.z); hb4.w = rne_bf16(res.w);
    *reinterpret_cast<ushort4*>(&hb[(size_t)n * 64 + f0]) = hb4;
    if (initmax) {
        *reinterpret_cast<float4*>(&hmax[(size_t)n * 64 + f0]) = res;
    } else {
        float4 hm = *reinterpret_cast<const float4*>(&hmax[(size_t)n * 64 + f0]);
        hm.x = fmaxf(hm.x, res.x);
        hm.y = fmaxf(hm.y, res.y);
        hm.z = fmaxf(hm.z, res.z);
        hm.w = fmaxf(hm.w, res.w);
        *reinterpret_cast<float4*>(&hmax[(size_t)n * 64 + f0]) = hm;
    }
}

// ---------------- gate MLP per node ----------------
__global__ __launch_bounds__(256) void gate_kernel(const float* __restrict__ h, fp g1W, fp g1b, fp g2W,
                                                   fp g2b, float* __restrict__ gate) {
    __shared__ float hs[4][64];
    int w = threadIdx.x >> 6, lane = threadIdx.x & 63;
    int n = blockIdx.x * 4 + w;
    hs[w][lane] = h[(size_t)n * 64 + lane];
    __syncthreads();
    float a = 0.f;
    for (int f = 0; f < 64; ++f) a += hs[w][f] * g1W[f * 64 + lane];
    a = fmaxf(a + g1b[lane], 0.f);
    float val = a * g2W[lane];
#pragma unroll
    for (int off = 32; off; off >>= 1) val += __shfl_xor(val, off);
    if (lane == 0) gate[n] = val + g2b[0];
}

// ---------------- graph boundaries ----------------
__global__ __launch_bounds__(256) void starts_kernel(const int* __restrict__ batch, int* __restrict__ starts) {
    int i = blockIdx.x * 256 + threadIdx.x;
    if (i >= N_NODES) return;
    if (i == 0) {
        int b = batch[0];
        for (int g = 0; g <= b && g <= N_GRAPHS; ++g) starts[g] = 0;
    } else {
        int b0 = batch[i - 1], b1 = batch[i];
        for (int g = b0 + 1; g <= b1 && g <= N_GRAPHS; ++g) starts[g] = i;
    }
    if (i == N_NODES - 1) {
        int b = batch[i];
        for (int g = b + 1; g <= N_GRAPHS; ++g) starts[g] = N_NODES;
    }
}

// ---------------- gated softmax pooling ----------------
__global__ __launch_bounds__(256) void pool_kernel(const float* __restrict__ h, const float* __restrict__ gate,
                                                   const int* __restrict__ starts, float* __restrict__ pooled) {
    int g = blockIdx.x;
    int beg = starts[g], end = starts[g + 1];
    int tid = threadIdx.x, lane = tid & 63, w = tid >> 6;
    __shared__ float red[4];
    __shared__ float accs[4][64];
    float m = -INFINITY;
    for (int i = beg + tid; i < end; i += 256) m = fmaxf(m, gate[i]);
#pragma unroll
    for (int off = 32; off; off >>= 1) m = fmaxf(m, __shfl_xor(m, off));
    if (lane == 0) red[w] = m;
    __syncthreads();
    m = fmaxf(fmaxf(red[0], red[1]), fmaxf(red[2], red[3]));
    __syncthreads();
    float s = 0.f;
    for (int i = beg + tid; i < end; i += 256) s += __expf(gate[i] - m);
#pragma unroll
    for (int off = 32; off; off >>= 1) s += __shfl_xor(s, off);
    if (lane == 0) red[w] = s;
    __syncthreads();
    s = red[0] + red[1] + red[2] + red[3] + 1e-16f;
    float acc = 0.f;
    for (int i = beg + w; i < end; i += 4) {
        float p = __expf(gate[i] - m);
        acc += p * h[(size_t)i * 64 + lane];
    }
    accs[w][lane] = acc;
    __syncthreads();
    if (w == 0) pooled[g * 64 + lane] = (accs[0][lane] + accs[1][lane] + accs[2][lane] + accs[3][lane]) / s;
}

// ---------------- 6-expert MLP head (f32 output) ----------------
__global__ __launch_bounds__(256) void mlp_kernel(const float* __restrict__ pooled, fp m0W, fp m0b, fp m1W,
                                                  fp m1b, fp m2W, fp m2b, fp m3W, fp m3b,
                                                  float* __restrict__ out) {
    int e = blockIdx.x, tid = threadIdx.x;
    __shared__ float P[64 * 64];
    __shared__ float A1[64 * 32];
    __shared__ float A2[64 * 16];
    __shared__ float A3[64 * 8];
    for (int i = tid; i < 64 * 64; i += 256) P[i] = pooled[i];
    __syncthreads();
    fp W0 = m0W + e * 64 * 32; fp B0 = m0b + e * 32;
    for (int i = tid; i < 64 * 32; i += 256) {
        int g = i >> 5, c = i & 31;
        float a = B0[c];
        for (int f = 0; f < 64; ++f) a += P[g * 64 + f] * W0[f * 32 + c];
        A1[i] = a > 0.f ? a : (__expf(a) - 1.f);
    }
    __syncthreads();
    fp W1 = m1W + e * 32 * 16; fp B1 = m1b + e * 16;
    for (int i = tid; i < 64 * 16; i += 256) {
        int g = i >> 4, c = i & 15;
        float a = B1[c];
        for (int f = 0; f < 32; ++f) a += A1[g * 32 + f] * W1[f * 16 + c];
        A2[i] = a > 0.f ? a : (__expf(a) - 1.f);
    }
    __syncthreads();
    fp W2 = m2W + e * 16 * 8; fp B2 = m2b + e * 8;
    for (int i = tid; i < 64 * 8; i += 256) {
        int g = i >> 3, c = i & 7;
        float a = B2[c];
        for (int f = 0; f < 16; ++f) a += A2[g * 16 + f] * W2[f * 8 + c];
        A3[i] = a > 0.f ? a : (__expf(a) - 1.f);
    }
    __syncthreads();
    fp W3 = m3W + e * 8;
    if (tid < 64) {
        int g = tid;
        float a = m3b[e];
        for (int j = 0; j < 8; ++j) a += A3[g * 8 + j] * W3[j];
        out[g * 6 + e] = a;
    }
}

__global__ __launch_bounds__(64) void loss_kernel(const float* __restrict__ preds, fp y,
                                                  float* __restrict__ out) {
    int lane = threadIdx.x;
    float lsum = 0.f;
    if (lane < 6) {
        float acc = 0.f;
        for (int g = 0; g < 64; ++g) {
            float d = preds[g * 6 + lane] - y[g * 6 + lane];
            acc += d * d;
        }
        lsum = sqrtf(acc / 64.f);
    }
#pragma unroll
    for (int off = 32; off; off >>= 1) lsum += __shfl_xor(lsum, off);
    if (lane == 0) out[384] = lsum;
}

extern "C" void kernel_launch(void* const* d_in, const int* in_sizes, int n_in, void* d_out, int out_size,
                              void* d_ws, size_t ws_size, hipStream_t stream) {
    bool dictOrder = (in_sizes[1] == 2 * N_EDGES);
    int iEI = dictOrder ? 1 : 33;
    int iEA = dictOrder ? 2 : 1;
    int iBT = dictOrder ? 3 : 34;
    int iY  = dictOrder ? 4 : 2;
    int w0  = dictOrder ? 5 : 3;

    fp x = (fp)d_in[0];
    const int* ei = (const int*)d_in[iEI];
    fp eattr = (fp)d_in[iEA];
    const int* batch = (const int*)d_in[iBT];
    fp y = (fp)d_in[iY];
    fp Wq0 = (fp)d_in[w0 + 0], bq0 = (fp)d_in[w0 + 1], Wk0 = (fp)d_in[w0 + 2], bk0 = (fp)d_in[w0 + 3];
    fp Wv0 = (fp)d_in[w0 + 4], bv0 = (fp)d_in[w0 + 5], We0 = (fp)d_in[w0 + 6];
    fp Ws0 = (fp)d_in[w0 + 7], bs0 = (fp)d_in[w0 + 8];
    fp Wq = (fp)d_in[w0 + 9], bq = (fp)d_in[w0 + 10], Wk = (fp)d_in[w0 + 11], bk = (fp)d_in[w0 + 12];
    fp Wv = (fp)d_in[w0 + 13], bv = (fp)d_in[w0 + 14], Wel = (fp)d_in[w0 + 15];
    fp Ws = (fp)d_in[w0 + 16], bs = (fp)d_in[w0 + 17];
    fp g1W = (fp)d_in[w0 + 18], g1b = (fp)d_in[w0 + 19], g2W = (fp)d_in[w0 + 20], g2b = (fp)d_in[w0 + 21];
    fp m0W = (fp)d_in[w0 + 22], m0b = (fp)d_in[w0 + 23], m1W = (fp)d_in[w0 + 24], m1b = (fp)d_in[w0 + 25];
    fp m2W = (fp)d_in[w0 + 26], m2b = (fp)d_in[w0 + 27], m3W = (fp)d_in[w0 + 28], m3b = (fp)d_in[w0 + 29];

    const int* srcArr = ei;
    const int* dstArr = ei + N_EDGES;

    char* wsp = (char*)d_ws;
    auto alloc = [&](size_t bytes) -> void* {
        void* p = (void*)wsp;
        wsp += (bytes + 255) & ~(size_t)255;
        return p;
    };
    float* q = (float*)alloc((size_t)N_NODES * 64 * 4);      // prescaled 1/8
    u16* kb = (u16*)alloc((size_t)N_NODES * 64 * 2);         // bf16
    u16* vb = (u16*)alloc((size_t)N_NODES * 64 * 2);         // bf16
    float* skb = (float*)alloc((size_t)N_NODES * 64 * 4);
    u16* hb = (u16*)alloc((size_t)N_NODES * 64 * 2);         // h bf16 (gemm A for layers 1-3)
    u16* xb = (u16*)alloc((size_t)N_NODES * IN_CH * 2);      // x bf16
    float* hmax = (float*)alloc((size_t)N_NODES * 64 * 4);
    float* qwe = (float*)alloc((size_t)N_NODES * 7 * 4);
    float* gate = (float*)alloc((size_t)N_NODES * 4);
    float* pooled = (float*)alloc(64 * 64 * 4);
    int* row_ptr = (int*)alloc((N_NODES + 1) * 4);
    int* cursor = (int*)alloc((size_t)N_NODES * 4);
    int* csr_src = (int*)alloc((size_t)N_EDGES * 4);
    int* csr_eid = (int*)alloc((size_t)N_EDGES * 4);
    float* ea_csr = (float*)alloc((size_t)N_EDGES * 7 * 4);
    u16* Bp0 = (u16*)alloc((size_t)(IN_CH / 32) * 16 * 512 * 2);
    u16* Bp1 = (u16*)alloc((size_t)(DIM / 32) * 16 * 512 * 2);
    u16* Bp2 = (u16*)alloc((size_t)(DIM / 32) * 16 * 512 * 2);
    u16* Bp3 = (u16*)alloc((size_t)(DIM / 32) * 16 * 512 * 2);
    int* blksum = (int*)alloc(256 * 4);
    int* starts = (int*)alloc((N_GRAPHS + 1) * 4);
    (void)ws_size;
    (void)n_in;

    float* outF = (float*)d_out;  // [0..383] preds, [384] total_loss

    // ---- CSR build (by dst) + weight/x conversion ----
    hipMemsetAsync(cursor, 0, (size_t)N_NODES * 4, stream);
    count_kernel<<<(N_EDGES + 255) / 256, 256, 0, stream>>>(dstArr, cursor);
    scan1_kernel<<<NBLK, 512, 0, stream>>>(cursor, row_ptr, blksum);
    scan2_kernel<<<1, 256, 0, stream>>>(blksum);
    scan3_kernel<<<NBLK, 512, 0, stream>>>(row_ptr, blksum, cursor);
    scatter_kernel<<<(N_EDGES + 255) / 256, 256, 0, stream>>>(srcArr, dstArr, cursor, csr_src, csr_eid);
    permute_ea_kernel<<<(N_EDGES + 255) / 256, 256, 0, stream>>>(eattr, csr_eid, ea_csr);
    cvt_bf16_kernel<<<(N_NODES * IN_CH / 4 + 255) / 256, 256, 0, stream>>>(x, xb, N_NODES * IN_CH / 4);
    packW_kernel<<<((IN_CH / 32) * 16 * 512 + 255) / 256, 256, 0, stream>>>(Wq0, Wk0, Wv0, Ws0, Bp0, IN_CH);
    u16* Bps[3] = {Bp1, Bp2, Bp3};
    for (int i = 0; i < N_CONVS; ++i)
        packW_kernel<<<((DIM / 32) * 16 * 512 + 255) / 256, 256, 0, stream>>>(
            Wq + i * 4096, Wk + i * 4096, Wv + i * 4096, Ws + i * 4096, Bps[i], DIM);

    int nodeGrid = N_NODES / 16;
    // layer 0 (conv_first, 128 -> 64), ELU, init hmax
    gemm_mfma_kernel<IN_CH><<<N_NODES / 32, 256, 0, stream>>>(xb, Bp0, bq0, bk0, bv0, bs0, q, kb, vb, skb);
    qwe_kernel<<<N_NODES * 64 / 256, 256, 0, stream>>>(q, We0, qwe);
    node_kernel<<<nodeGrid, 256, 0, stream>>>(q, kb, vb, skb, qwe, ea_csr, We0, row_ptr, csr_src,
                                              hb, hmax, 1, 1);
    // layers 1..3 (64 -> 64); ELU except last; JK running max
    for (int i = 0; i < N_CONVS; ++i) {
        gemm_mfma_kernel<DIM><<<N_NODES / 32, 256, 0, stream>>>(hb, Bps[i], bq + i * 64, bk + i * 64,
                                                                bv + i * 64, bs + i * 64, q, kb, vb, skb);
        qwe_kernel<<<N_NODES * 64 / 256, 256, 0, stream>>>(q, Wel + i * 448, qwe);
        node_kernel<<<nodeGrid, 256, 0, stream>>>(q, kb, vb, skb, qwe, ea_csr, Wel + i * 448, row_ptr,
                                                  csr_src, hb, hmax, (i < N_CONVS - 1) ? 1 : 0, 0);
    }
    // pooling head
    gate_kernel<<<N_NODES / 4, 256, 0, stream>>>(hmax, g1W, g1b, g2W, g2b, gate);
    starts_kernel<<<(N_NODES + 255) / 256, 256, 0, stream>>>(batch, starts);
    pool_kernel<<<N_GRAPHS, 256, 0, stream>>>(hmax, gate, starts, pooled);
    mlp_kernel<<<6, 256, 0, stream>>>(pooled, m0W, m0b, m1W, m1b, m2W, m2b, m3W, m3b, outF);
    loss_kernel<<<1, 64, 0, stream>>>(outF, y, outF);
}

// Round 10
// 931.982 us; speedup vs baseline: 1.8331x; 1.3078x over previous
//
#include <hip/hip_runtime.h>
#include <math.h>

#define N_NODES 100000
#define N_EDGES 1600000
#define N_GRAPHS 64
#define IN_CH 128
#define DIM 64
#define N_CONVS 3
#define NBLK 196  // ceil(100000/512)

typedef const float* fp;
typedef unsigned int u32;
typedef unsigned short u16;
typedef __attribute__((ext_vector_type(8))) short short8v;
typedef __attribute__((ext_vector_type(4))) float f32x4;

__device__ inline u16 rne_bf16(float f) {
    u32 u = __float_as_uint(f);
    return (u16)((u + 0x7fffu + ((u >> 16) & 1u)) >> 16);
}
__device__ inline float bf16lo_f(u32 w) { return __uint_as_float(w << 16); }
__device__ inline float bf16hi_f(u32 w) { return __uint_as_float(w & 0xffff0000u); }

// ---------------- CSR build ----------------
__global__ __launch_bounds__(256) void count_kernel(const int* __restrict__ dst, int* __restrict__ cnt) {
    int j = blockIdx.x * 256 + threadIdx.x;
    if (j < N_EDGES) {
        int d = dst[j];
        if ((unsigned)d < N_NODES) atomicAdd(&cnt[d], 1);
    }
}

__global__ __launch_bounds__(512) void scan1_kernel(const int* __restrict__ cnt, int* __restrict__ rp,
                                                    int* __restrict__ blksum) {
    __shared__ int tmp[512];
    int t = threadIdx.x, i = blockIdx.x * 512 + t;
    int v0 = (i < N_NODES) ? cnt[i] : 0;
    tmp[t] = v0;
    __syncthreads();
    for (int off = 1; off < 512; off <<= 1) {
        int add = (t >= off) ? tmp[t - off] : 0;
        __syncthreads();
        tmp[t] += add;
        __syncthreads();
    }
    if (i < N_NODES) rp[i] = tmp[t] - v0;
    if (t == 511) blksum[blockIdx.x] = tmp[511];
}

__global__ __launch_bounds__(256) void scan2_kernel(int* __restrict__ blksum) {
    __shared__ int tmp[256];
    int t = threadIdx.x;
    int v0 = (t < NBLK) ? blksum[t] : 0;
    tmp[t] = v0;
    __syncthreads();
    for (int off = 1; off < 256; off <<= 1) {
        int add = (t >= off) ? tmp[t - off] : 0;
        __syncthreads();
        tmp[t] += add;
        __syncthreads();
    }
    if (t < NBLK) blksum[t] = tmp[t] - v0;
}

__global__ __launch_bounds__(512) void scan3_kernel(int* __restrict__ rp, const int* __restrict__ blksum,
                                                    int* __restrict__ cursor) {
    int t = threadIdx.x, i = blockIdx.x * 512 + t;
    if (i < N_NODES) {
        int v = rp[i] + blksum[blockIdx.x];
        rp[i] = v;
        cursor[i] = v;
    }
    if (i == 0) rp[N_NODES] = N_EDGES;
}

// single 8B random store per edge (src, eid)
__global__ __launch_bounds__(256) void scatter_kernel(const int* __restrict__ src, const int* __restrict__ dst,
                                                      int* __restrict__ cursor, int2* __restrict__ csr_se) {
    int j = blockIdx.x * 256 + threadIdx.x;
    if (j < N_EDGES) {
        int d = dst[j];
        if ((unsigned)d >= N_NODES) return;
        int pos = atomicAdd(&cursor[d], 1);
        if ((unsigned)pos < N_EDGES) {
            int s = src[j];
            csr_se[pos] = make_int2(((unsigned)s < N_NODES) ? s : 0, j);
        }
    }
}

// split csr_se into csr_src (int) + eab (uint4: 7 bf16 ea + pad), both coalesced writes
__global__ __launch_bounds__(256) void build_csr_kernel(const int2* __restrict__ csr_se, fp ea,
                                                        int* __restrict__ csr_src, uint4* __restrict__ eab) {
    int p = blockIdx.x * 256 + threadIdx.x;
    if (p < N_EDGES) {
        int2 se = csr_se[p];
        csr_src[p] = se.x;
        size_t sb = (size_t)se.y * 7;
        u16 b[8];
#pragma unroll
        for (int c = 0; c < 7; ++c) b[c] = rne_bf16(ea[sb + c]);
        b[7] = 0;
        uint4 o;
        o.x = b[0] | ((u32)b[1] << 16);
        o.y = b[2] | ((u32)b[3] << 16);
        o.z = b[4] | ((u32)b[5] << 16);
        o.w = b[6] | ((u32)b[7] << 16);
        eab[p] = o;
    }
}

// ---------------- x -> bf16 ----------------
__global__ __launch_bounds__(256) void cvt_bf16_kernel(const float* __restrict__ in, u16* __restrict__ out,
                                                       int n4) {
    int i = blockIdx.x * 256 + threadIdx.x;
    if (i < n4) {
        float4 v = reinterpret_cast<const float4*>(in)[i];
        ushort4 o;
        o.x = rne_bf16(v.x); o.y = rne_bf16(v.y); o.z = rne_bf16(v.z); o.w = rne_bf16(v.w);
        reinterpret_cast<ushort4*>(out)[i] = o;
    }
}

// ---------------- pack W (q|k|v|s -> K x 256) into MFMA B-fragment order ----------------
__global__ __launch_bounds__(256) void packW_kernel(fp Wq, fp Wk, fp Wv, fp Ws, u16* __restrict__ Bp,
                                                    int K) {
    int total = (K / 32) * 16 * 512;
    int tid = blockIdx.x * 256 + threadIdx.x;
    if (tid >= total) return;
    int j = tid & 7, l = (tid >> 3) & 63, fragid = tid >> 9;
    int tk = fragid >> 4, gtn = fragid & 15;
    int k = tk * 32 + ((l >> 4) << 3) + j;
    int n = (gtn << 4) + (l & 15);
    int mat = n >> 6, cn = n & 63;
    fp W = mat == 0 ? Wq : mat == 1 ? Wk : mat == 2 ? Wv : Ws;
    Bp[tid] = rne_bf16(W[k * 64 + cn]);
}

// ---------------- fused MFMA GEMM: q(f32*1/8) | k(bf16) | v(bf16) | skip(f32) ----------------
template <int K>
__global__ __launch_bounds__(256) void gemm_mfma_kernel(
    const u16* __restrict__ A, const u16* __restrict__ Bp,
    fp bq, fp bk, fp bv, fp bs,
    float* __restrict__ q, u16* __restrict__ kb, u16* __restrict__ vb, float* __restrict__ skb) {
    constexpr int NTK = K / 32;
    int wave = threadIdx.x >> 6;  // 0:q 1:k 2:v 3:skip
    int l = threadIdx.x & 63;
    int lr = l & 15, lg = l >> 4;
    int row0 = blockIdx.x * 32;
    short8v a[2][NTK];
#pragma unroll
    for (int mi = 0; mi < 2; ++mi)
#pragma unroll
        for (int tk = 0; tk < NTK; ++tk)
            a[mi][tk] = *reinterpret_cast<const short8v*>(
                &A[(size_t)(row0 + mi * 16 + lr) * K + tk * 32 + lg * 8]);
    f32x4 c[2][4] = {};
#pragma unroll
    for (int tn = 0; tn < 4; ++tn) {
        int gtn = wave * 4 + tn;
#pragma unroll
        for (int tk = 0; tk < NTK; ++tk) {
            short8v b = *reinterpret_cast<const short8v*>(&Bp[((size_t)(tk * 16 + gtn) * 64 + l) * 8]);
            c[0][tn] = __builtin_amdgcn_mfma_f32_16x16x32_bf16(a[0][tk], b, c[0][tn], 0, 0, 0);
            c[1][tn] = __builtin_amdgcn_mfma_f32_16x16x32_bf16(a[1][tk], b, c[1][tn], 0, 0, 0);
        }
    }
    fp bias = wave == 0 ? bq : wave == 1 ? bk : wave == 2 ? bv : bs;
#pragma unroll
    for (int tn = 0; tn < 4; ++tn) {
        int cl = tn * 16 + lr;
        float bb = bias[cl];
#pragma unroll
        for (int mi = 0; mi < 2; ++mi)
#pragma unroll
            for (int r = 0; r < 4; ++r) {
                size_t row = row0 + mi * 16 + lg * 4 + r;
                float val = c[mi][tn][r] + bb;
                if (wave == 0) q[row * 64 + cl] = val * 0.125f;
                else if (wave == 3) skb[row * 64 + cl] = val;
                else if (wave == 1) kb[row * 64 + cl] = rne_bf16(val);
                else vb[row * 64 + cl] = rne_bf16(val);
            }
    }
}

// ---------------- per-node edge aggregation: 16-lane groups, bf16 k/v/ea, inline qwe ----------------
__global__ __launch_bounds__(256) void node_kernel(
    const float* __restrict__ qs, const u16* __restrict__ kb, const u16* __restrict__ vb,
    const float* __restrict__ skb, const uint4* __restrict__ eab, fp We,
    const int* __restrict__ row_ptr, const int* __restrict__ csr_src,
    u16* __restrict__ hb, float* __restrict__ hmax, int act, int initmax) {
    int tid = threadIdx.x;
    int lane = tid & 63;
    int g = lane >> 4, fl = lane & 15;
    int gbase = g << 4;
    int n = blockIdx.x * 16 + (tid >> 6) * 4 + g;
    int f0 = fl * 4;
    float4 q4 = *reinterpret_cast<const float4*>(&qs[(size_t)n * 64 + f0]);
    // inline qwe: qw[c] = sum_f q[f]*We[c][f], via 16-lane reduce (q prescaled 1/8)
    float qw[7];
#pragma unroll
    for (int c = 0; c < 7; ++c) {
        float4 w4 = *reinterpret_cast<const float4*>(&We[c * 64 + f0]);
        float t = q4.x * w4.x + q4.y * w4.y + q4.z * w4.z + q4.w * w4.w;
        t += __shfl_xor(t, 1);
        t += __shfl_xor(t, 2);
        t += __shfl_xor(t, 4);
        t += __shfl_xor(t, 8);
        qw[c] = t;
    }
    int beg = row_ptr[n], end = row_ptr[n + 1];
    float s = 0.f;
    float ax = 0.f, ay = 0.f, az = 0.f, aw = 0.f;
    float r[7];
#pragma unroll
    for (int c = 0; c < 7; ++c) r[c] = 0.f;

    for (int p = beg; p < end; p += 4) {
        int svi = p + (fl & 3);
        svi = svi < end ? svi : end - 1;
        int sv = csr_src[svi];
#pragma unroll
        for (int j = 0; j < 4; ++j) {
            int pj = p + j;
            int pc = pj < end ? pj : end - 1;
            int sn = __shfl(sv, gbase + j);
            uint2 k2 = *reinterpret_cast<const uint2*>(&kb[(size_t)sn * 64 + f0]);
            uint2 v2 = *reinterpret_cast<const uint2*>(&vb[(size_t)sn * 64 + f0]);
            uint4 e4 = eab[pc];
            float e0 = bf16lo_f(e4.x), e1 = bf16hi_f(e4.x);
            float e2 = bf16lo_f(e4.y), e3 = bf16hi_f(e4.y);
            float e4f = bf16lo_f(e4.z), e5 = bf16hi_f(e4.z);
            float e6 = bf16lo_f(e4.w);
            float al = qw[0] * e0 + qw[1] * e1 + qw[2] * e2 + qw[3] * e3 +
                       qw[4] * e4f + qw[5] * e5 + qw[6] * e6;
            float kf0 = bf16lo_f(k2.x), kf1 = bf16hi_f(k2.x);
            float kf2 = bf16lo_f(k2.y), kf3 = bf16hi_f(k2.y);
            float vf0 = bf16lo_f(v2.x), vf1 = bf16hi_f(v2.x);
            float vf2 = bf16lo_f(v2.y), vf3 = bf16hi_f(v2.y);
            float d = q4.x * kf0 + q4.y * kf1 + q4.z * kf2 + q4.w * kf3;
            d += __shfl_xor(d, 1);
            d += __shfl_xor(d, 2);
            d += __shfl_xor(d, 4);
            d += __shfl_xor(d, 8);
            float pe = (pj < end) ? __expf(al + d) : 0.f;
            s += pe;
            ax += pe * vf0; ay += pe * vf1; az += pe * vf2; aw += pe * vf3;
            r[0] += pe * e0; r[1] += pe * e1; r[2] += pe * e2; r[3] += pe * e3;
            r[4] += pe * e4f; r[5] += pe * e5; r[6] += pe * e6;
        }
    }
    float inv = 1.f / (s + 1e-16f);
    float o0 = ax, o1 = ay, o2 = az, o3 = aw;
#pragma unroll
    for (int c = 0; c < 7; ++c) {
        o0 += We[c * 64 + f0 + 0] * r[c];
        o1 += We[c * 64 + f0 + 1] * r[c];
        o2 += We[c * 64 + f0 + 2] * r[c];
        o3 += We[c * 64 + f0 + 3] * r[c];
    }
    float4 sk4 = *reinterpret_cast<const float4*>(&skb[(size_t)n * 64 + f0]);
    float4 res;
    res.x = o0 * inv + sk4.x;
    res.y = o1 * inv + sk4.y;
    res.z = o2 * inv + sk4.z;
    res.w = o3 * inv + sk4.w;
    if (act) {
        res.x = res.x > 0.f ? res.x : (__expf(res.x) - 1.f);
        res.y = res.y > 0.f ? res.y : (__expf(res.y) - 1.f);
        res.z = res.z > 0.f ? res.z : (__expf(res.z) - 1.f);
        res.w = res.w > 0.f ? res.w : (__expf(res.w) - 1.f);
    }
    ushort4 hb4;
    hb4.x = rne_bf16(res.x); hb4.y = rne_bf16(res.y); hb4.z = rne_bf16(res.z); hb4.w = rne_bf16(res.w);
    *reinterpret_cast<ushort4*>(&hb[(size_t)n * 64 + f0]) = hb4;
    if (initmax) {
        *reinterpret_cast<float4*>(&hmax[(size_t)n * 64 + f0]) = res;
    } else {
        float4 hm = *reinterpret_cast<const float4*>(&hmax[(size_t)n * 64 + f0]);
        hm.x = fmaxf(hm.x, res.x);
        hm.y = fmaxf(hm.y, res.y);
        hm.z = fmaxf(hm.z, res.z);
        hm.w = fmaxf(hm.w, res.w);
        *reinterpret_cast<float4*>(&hmax[(size_t)n * 64 + f0]) = hm;
    }
}

// ---------------- gate MLP per node ----------------
__global__ __launch_bounds__(256) void gate_kernel(const float* __restrict__ h, fp g1W, fp g1b, fp g2W,
                                                   fp g2b, float* __restrict__ gate) {
    __shared__ float hs[4][64];
    int w = threadIdx.x >> 6, lane = threadIdx.x & 63;
    int n = blockIdx.x * 4 + w;
    hs[w][lane] = h[(size_t)n * 64 + lane];
    __syncthreads();
    float a = 0.f;
    for (int f = 0; f < 64; ++f) a += hs[w][f] * g1W[f * 64 + lane];
    a = fmaxf(a + g1b[lane], 0.f);
    float val = a * g2W[lane];
#pragma unroll
    for (int off = 32; off; off >>= 1) val += __shfl_xor(val, off);
    if (lane == 0) gate[n] = val + g2b[0];
}

// ---------------- graph boundaries ----------------
__global__ __launch_bounds__(256) void starts_kernel(const int* __restrict__ batch, int* __restrict__ starts) {
    int i = blockIdx.x * 256 + threadIdx.x;
    if (i >= N_NODES) return;
    if (i == 0) {
        int b = batch[0];
        for (int g = 0; g <= b && g <= N_GRAPHS; ++g) starts[g] = 0;
    } else {
        int b0 = batch[i - 1], b1 = batch[i];
        for (int g = b0 + 1; g <= b1 && g <= N_GRAPHS; ++g) starts[g] = i;
    }
    if (i == N_NODES - 1) {
        int b = batch[i];
        for (int g = b + 1; g <= N_GRAPHS; ++g) starts[g] = N_NODES;
    }
}

// ---------------- gated softmax pooling ----------------
__global__ __launch_bounds__(256) void pool_kernel(const float* __restrict__ h, const float* __restrict__ gate,
                                                   const int* __restrict__ starts, float* __restrict__ pooled) {
    int g = blockIdx.x;
    int beg = starts[g], end = starts[g + 1];
    int tid = threadIdx.x, lane = tid & 63, w = tid >> 6;
    __shared__ float red[4];
    __shared__ float accs[4][64];
    float m = -INFINITY;
    for (int i = beg + tid; i < end; i += 256) m = fmaxf(m, gate[i]);
#pragma unroll
    for (int off = 32; off; off >>= 1) m = fmaxf(m, __shfl_xor(m, off));
    if (lane == 0) red[w] = m;
    __syncthreads();
    m = fmaxf(fmaxf(red[0], red[1]), fmaxf(red[2], red[3]));
    __syncthreads();
    float s = 0.f;
    for (int i = beg + tid; i < end; i += 256) s += __expf(gate[i] - m);
#pragma unroll
    for (int off = 32; off; off >>= 1) s += __shfl_xor(s, off);
    if (lane == 0) red[w] = s;
    __syncthreads();
    s = red[0] + red[1] + red[2] + red[3] + 1e-16f;
    float acc = 0.f;
    for (int i = beg + w; i < end; i += 4) {
        float p = __expf(gate[i] - m);
        acc += p * h[(size_t)i * 64 + lane];
    }
    accs[w][lane] = acc;
    __syncthreads();
    if (w == 0) pooled[g * 64 + lane] = (accs[0][lane] + accs[1][lane] + accs[2][lane] + accs[3][lane]) / s;
}

// ---------------- 6-expert MLP head (f32 output) ----------------
__global__ __launch_bounds__(256) void mlp_kernel(const float* __restrict__ pooled, fp m0W, fp m0b, fp m1W,
                                                  fp m1b, fp m2W, fp m2b, fp m3W, fp m3b,
                                                  float* __restrict__ out) {
    int e = blockIdx.x, tid = threadIdx.x;
    __shared__ float P[64 * 64];
    __shared__ float A1[64 * 32];
    __shared__ float A2[64 * 16];
    __shared__ float A3[64 * 8];
    for (int i = tid; i < 64 * 64; i += 256) P[i] = pooled[i];
    __syncthreads();
    fp W0 = m0W + e * 64 * 32; fp B0 = m0b + e * 32;
    for (int i = tid; i < 64 * 32; i += 256) {
        int g = i >> 5, c = i & 31;
        float a = B0[c];
        for (int f = 0; f < 64; ++f) a += P[g * 64 + f] * W0[f * 32 + c];
        A1[i] = a > 0.f ? a : (__expf(a) - 1.f);
    }
    __syncthreads();
    fp W1 = m1W + e * 32 * 16; fp B1 = m1b + e * 16;
    for (int i = tid; i < 64 * 16; i += 256) {
        int g = i >> 4, c = i & 15;
        float a = B1[c];
        for (int f = 0; f < 32; ++f) a += A1[g * 32 + f] * W1[f * 16 + c];
        A2[i] = a > 0.f ? a : (__expf(a) - 1.f);
    }
    __syncthreads();
    fp W2 = m2W + e * 16 * 8; fp B2 = m2b + e * 8;
    for (int i = tid; i < 64 * 8; i += 256) {
        int g = i >> 3, c = i & 7;
        float a = B2[c];
        for (int f = 0; f < 16; ++f) a += A2[g * 16 + f] * W2[f * 8 + c];
        A3[i] = a > 0.f ? a : (__expf(a) - 1.f);
    }
    __syncthreads();
    fp W3 = m3W + e * 8;
    if (tid < 64) {
        int g = tid;
        float a = m3b[e];
        for (int j = 0; j < 8; ++j) a += A3[g * 8 + j] * W3[j];
        out[g * 6 + e] = a;
    }
}

__global__ __launch_bounds__(64) void loss_kernel(const float* __restrict__ preds, fp y,
                                                  float* __restrict__ out) {
    int lane = threadIdx.x;
    float lsum = 0.f;
    if (lane < 6) {
        float acc = 0.f;
        for (int g = 0; g < 64; ++g) {
            float d = preds[g * 6 + lane] - y[g * 6 + lane];
            acc += d * d;
        }
        lsum = sqrtf(acc / 64.f);
    }
#pragma unroll
    for (int off = 32; off; off >>= 1) lsum += __shfl_xor(lsum, off);
    if (lane == 0) out[384] = lsum;
}

extern "C" void kernel_launch(void* const* d_in, const int* in_sizes, int n_in, void* d_out, int out_size,
                              void* d_ws, size_t ws_size, hipStream_t stream) {
    bool dictOrder = (in_sizes[1] == 2 * N_EDGES);
    int iEI = dictOrder ? 1 : 33;
    int iEA = dictOrder ? 2 : 1;
    int iBT = dictOrder ? 3 : 34;
    int iY  = dictOrder ? 4 : 2;
    int w0  = dictOrder ? 5 : 3;

    fp x = (fp)d_in[0];
    const int* ei = (const int*)d_in[iEI];
    fp eattr = (fp)d_in[iEA];
    const int* batch = (const int*)d_in[iBT];
    fp y = (fp)d_in[iY];
    fp Wq0 = (fp)d_in[w0 + 0], bq0 = (fp)d_in[w0 + 1], Wk0 = (fp)d_in[w0 + 2], bk0 = (fp)d_in[w0 + 3];
    fp Wv0 = (fp)d_in[w0 + 4], bv0 = (fp)d_in[w0 + 5], We0 = (fp)d_in[w0 + 6];
    fp Ws0 = (fp)d_in[w0 + 7], bs0 = (fp)d_in[w0 + 8];
    fp Wq = (fp)d_in[w0 + 9], bq = (fp)d_in[w0 + 10], Wk = (fp)d_in[w0 + 11], bk = (fp)d_in[w0 + 12];
    fp Wv = (fp)d_in[w0 + 13], bv = (fp)d_in[w0 + 14], Wel = (fp)d_in[w0 + 15];
    fp Ws = (fp)d_in[w0 + 16], bs = (fp)d_in[w0 + 17];
    fp g1W = (fp)d_in[w0 + 18], g1b = (fp)d_in[w0 + 19], g2W = (fp)d_in[w0 + 20], g2b = (fp)d_in[w0 + 21];
    fp m0W = (fp)d_in[w0 + 22], m0b = (fp)d_in[w0 + 23], m1W = (fp)d_in[w0 + 24], m1b = (fp)d_in[w0 + 25];
    fp m2W = (fp)d_in[w0 + 26], m2b = (fp)d_in[w0 + 27], m3W = (fp)d_in[w0 + 28], m3b = (fp)d_in[w0 + 29];

    const int* srcArr = ei;
    const int* dstArr = ei + N_EDGES;

    char* wsp = (char*)d_ws;
    auto alloc = [&](size_t bytes) -> void* {
        void* p = (void*)wsp;
        wsp += (bytes + 255) & ~(size_t)255;
        return p;
    };
    float* q = (float*)alloc((size_t)N_NODES * 64 * 4);      // prescaled 1/8
    u16* kb = (u16*)alloc((size_t)N_NODES * 64 * 2);         // bf16
    u16* vb = (u16*)alloc((size_t)N_NODES * 64 * 2);         // bf16
    float* skb = (float*)alloc((size_t)N_NODES * 64 * 4);
    u16* hb = (u16*)alloc((size_t)N_NODES * 64 * 2);         // h bf16 (gemm A for layers 1-3)
    u16* xb = (u16*)alloc((size_t)N_NODES * IN_CH * 2);      // x bf16
    float* hmax = (float*)alloc((size_t)N_NODES * 64 * 4);
    float* gate = (float*)alloc((size_t)N_NODES * 4);
    float* pooled = (float*)alloc(64 * 64 * 4);
    int* row_ptr = (int*)alloc((N_NODES + 1) * 4);
    int* cursor = (int*)alloc((size_t)N_NODES * 4);
    int2* csr_se = (int2*)alloc((size_t)N_EDGES * 8);
    int* csr_src = (int*)alloc((size_t)N_EDGES * 4);
    uint4* eab = (uint4*)alloc((size_t)N_EDGES * 16);
    u16* Bp0 = (u16*)alloc((size_t)(IN_CH / 32) * 16 * 512 * 2);
    u16* Bp1 = (u16*)alloc((size_t)(DIM / 32) * 16 * 512 * 2);
    u16* Bp2 = (u16*)alloc((size_t)(DIM / 32) * 16 * 512 * 2);
    u16* Bp3 = (u16*)alloc((size_t)(DIM / 32) * 16 * 512 * 2);
    int* blksum = (int*)alloc(256 * 4);
    int* starts = (int*)alloc((N_GRAPHS + 1) * 4);
    (void)ws_size;
    (void)n_in;

    float* outF = (float*)d_out;  // [0..383] preds, [384] total_loss

    // ---- CSR build (by dst) + weight/x conversion ----
    hipMemsetAsync(cursor, 0, (size_t)N_NODES * 4, stream);
    count_kernel<<<(N_EDGES + 255) / 256, 256, 0, stream>>>(dstArr, cursor);
    scan1_kernel<<<NBLK, 512, 0, stream>>>(cursor, row_ptr, blksum);
    scan2_kernel<<<1, 256, 0, stream>>>(blksum);
    scan3_kernel<<<NBLK, 512, 0, stream>>>(row_ptr, blksum, cursor);
    scatter_kernel<<<(N_EDGES + 255) / 256, 256, 0, stream>>>(srcArr, dstArr, cursor, csr_se);
    build_csr_kernel<<<(N_EDGES + 255) / 256, 256, 0, stream>>>(csr_se, eattr, csr_src, eab);
    cvt_bf16_kernel<<<(N_NODES * IN_CH / 4 + 255) / 256, 256, 0, stream>>>(x, xb, N_NODES * IN_CH / 4);
    packW_kernel<<<((IN_CH / 32) * 16 * 512 + 255) / 256, 256, 0, stream>>>(Wq0, Wk0, Wv0, Ws0, Bp0, IN_CH);
    u16* Bps[3] = {Bp1, Bp2, Bp3};
    for (int i = 0; i < N_CONVS; ++i)
        packW_kernel<<<((DIM / 32) * 16 * 512 + 255) / 256, 256, 0, stream>>>(
            Wq + i * 4096, Wk + i * 4096, Wv + i * 4096, Ws + i * 4096, Bps[i], DIM);

    int nodeGrid = N_NODES / 16;
    // layer 0 (conv_first, 128 -> 64), ELU, init hmax
    gemm_mfma_kernel<IN_CH><<<N_NODES / 32, 256, 0, stream>>>(xb, Bp0, bq0, bk0, bv0, bs0, q, kb, vb, skb);
    node_kernel<<<nodeGrid, 256, 0, stream>>>(q, kb, vb, skb, eab, We0, row_ptr, csr_src,
                                              hb, hmax, 1, 1);
    // layers 1..3 (64 -> 64); ELU except last; JK running max
    for (int i = 0; i < N_CONVS; ++i) {
        gemm_mfma_kernel<DIM><<<N_NODES / 32, 256, 0, stream>>>(hb, Bps[i], bq + i * 64, bk + i * 64,
                                                                bv + i * 64, bs + i * 64, q, kb, vb, skb);
        node_kernel<<<nodeGrid, 256, 0, stream>>>(q, kb, vb, skb, eab, Wel + i * 448, row_ptr,
                                                  csr_src, hb, hmax, (i < N_CONVS - 1) ? 1 : 0, 0);
    }
    // pooling head
    gate_kernel<<<N_NODES / 4, 256, 0, stream>>>(hmax, g1W, g1b, g2W, g2b, gate);
    starts_kernel<<<(N_NODES + 255) / 256, 256, 0, stream>>>(batch, starts);
    pool_kernel<<<N_GRAPHS, 256, 0, stream>>>(hmax, gate, starts, pooled);
    mlp_kernel<<<6, 256, 0, stream>>>(pooled, m0W, m0b, m1W, m1b, m2W, m2b, m3W, m3b, outF);
    loss_kernel<<<1, 64, 0, stream>>>(outF, y, outF);
}

// Round 11
// 898.243 us; speedup vs baseline: 1.9020x; 1.0376x over previous
//
#include <hip/hip_runtime.h>
#include <math.h>

#define N_NODES 100000
#define N_EDGES 1600000
#define N_GRAPHS 64
#define IN_CH 128
#define DIM 64
#define N_CONVS 3
#define NBLK 196      // ceil(100000/512)
#define NPASS 8
#define PASS_SZ 12500  // N_NODES / NPASS

typedef const float* fp;
typedef unsigned int u32;
typedef unsigned short u16;
typedef __attribute__((ext_vector_type(8))) short short8v;
typedef __attribute__((ext_vector_type(4))) float f32x4;

__device__ inline u16 rne_bf16(float f) {
    u32 u = __float_as_uint(f);
    return (u16)((u + 0x7fffu + ((u >> 16) & 1u)) >> 16);
}
__device__ inline float bf16lo_f(u32 w) { return __uint_as_float(w << 16); }
__device__ inline float bf16hi_f(u32 w) { return __uint_as_float(w & 0xffff0000u); }

// ---------------- CSR build ----------------
__global__ __launch_bounds__(256) void count_kernel(const int* __restrict__ dst, int* __restrict__ cnt) {
    int j = blockIdx.x * 256 + threadIdx.x;
    if (j < N_EDGES) {
        int d = dst[j];
        if ((unsigned)d < N_NODES) atomicAdd(&cnt[d], 1);
    }
}

__global__ __launch_bounds__(512) void scan1_kernel(const int* __restrict__ cnt, int* __restrict__ rp,
                                                    int* __restrict__ blksum) {
    __shared__ int tmp[512];
    int t = threadIdx.x, i = blockIdx.x * 512 + t;
    int v0 = (i < N_NODES) ? cnt[i] : 0;
    tmp[t] = v0;
    __syncthreads();
    for (int off = 1; off < 512; off <<= 1) {
        int add = (t >= off) ? tmp[t - off] : 0;
        __syncthreads();
        tmp[t] += add;
        __syncthreads();
    }
    if (i < N_NODES) rp[i] = tmp[t] - v0;
    if (t == 511) blksum[blockIdx.x] = tmp[511];
}

__global__ __launch_bounds__(256) void scan2_kernel(int* __restrict__ blksum) {
    __shared__ int tmp[256];
    int t = threadIdx.x;
    int v0 = (t < NBLK) ? blksum[t] : 0;
    tmp[t] = v0;
    __syncthreads();
    for (int off = 1; off < 256; off <<= 1) {
        int add = (t >= off) ? tmp[t - off] : 0;
        __syncthreads();
        tmp[t] += add;
        __syncthreads();
    }
    if (t < NBLK) blksum[t] = tmp[t] - v0;
}

__global__ __launch_bounds__(512) void scan3_kernel(int* __restrict__ rp, const int* __restrict__ blksum,
                                                    int* __restrict__ cursor) {
    int t = threadIdx.x, i = blockIdx.x * 512 + t;
    if (i < N_NODES) {
        int v = rp[i] + blksum[blockIdx.x];
        rp[i] = v;
        cursor[i] = v;
    }
    if (i == 0) rp[N_NODES] = N_EDGES;
}

// ea (f32 x7, original order) -> bf16-packed uint4 (original order), coalesced
__global__ __launch_bounds__(256) void cvt_ea_kernel(fp ea, uint4* __restrict__ eab_orig) {
    int j = blockIdx.x * 256 + threadIdx.x;
    if (j < N_EDGES) {
        size_t sb = (size_t)j * 7;
        u16 b[8];
#pragma unroll
        for (int c = 0; c < 7; ++c) b[c] = rne_bf16(ea[sb + c]);
        b[7] = 0;
        uint4 o;
        o.x = b[0] | ((u32)b[1] << 16);
        o.y = b[2] | ((u32)b[3] << 16);
        o.z = b[4] | ((u32)b[5] << 16);
        o.w = b[6] | ((u32)b[7] << 16);
        eab_orig[j] = o;
    }
}

// range-split scatter: only edges with dst in [lo, hi) — keeps the write window L2-resident
__global__ __launch_bounds__(256) void scatter_pass_kernel(const int* __restrict__ src,
                                                           const int* __restrict__ dst,
                                                           const uint4* __restrict__ eab_orig,
                                                           int* __restrict__ cursor,
                                                           int* __restrict__ csr_src,
                                                           uint4* __restrict__ eab, int lo, int hi) {
    int j = blockIdx.x * 256 + threadIdx.x;
    if (j < N_EDGES) {
        int d = dst[j];
        if (d < lo || d >= hi || (unsigned)d >= N_NODES) return;
        int pos = atomicAdd(&cursor[d], 1);
        if ((unsigned)pos < N_EDGES) {
            int s = src[j];
            csr_src[pos] = ((unsigned)s < N_NODES) ? s : 0;
            eab[pos] = eab_orig[j];
        }
    }
}

// ---------------- x -> bf16 ----------------
__global__ __launch_bounds__(256) void cvt_bf16_kernel(const float* __restrict__ in, u16* __restrict__ out,
                                                       int n4) {
    int i = blockIdx.x * 256 + threadIdx.x;
    if (i < n4) {
        float4 v = reinterpret_cast<const float4*>(in)[i];
        ushort4 o;
        o.x = rne_bf16(v.x); o.y = rne_bf16(v.y); o.z = rne_bf16(v.z); o.w = rne_bf16(v.w);
        reinterpret_cast<ushort4*>(out)[i] = o;
    }
}

// ---------------- pack W (q|k|v|s -> K x 256) into MFMA B-fragment order ----------------
__global__ __launch_bounds__(256) void packW_kernel(fp Wq, fp Wk, fp Wv, fp Ws, u16* __restrict__ Bp,
                                                    int K) {
    int total = (K / 32) * 16 * 512;
    int tid = blockIdx.x * 256 + threadIdx.x;
    if (tid >= total) return;
    int j = tid & 7, l = (tid >> 3) & 63, fragid = tid >> 9;
    int tk = fragid >> 4, gtn = fragid & 15;
    int k = tk * 32 + ((l >> 4) << 3) + j;
    int n = (gtn << 4) + (l & 15);
    int mat = n >> 6, cn = n & 63;
    fp W = mat == 0 ? Wq : mat == 1 ? Wk : mat == 2 ? Wv : Ws;
    Bp[tid] = rne_bf16(W[k * 64 + cn]);
}

// ---------------- fused MFMA GEMM: q(f32*1/8) | kv(packed bf16) | skip(f32) ----------------
template <int K>
__global__ __launch_bounds__(256) void gemm_mfma_kernel(
    const u16* __restrict__ A, const u16* __restrict__ Bp,
    fp bq, fp bk, fp bv, fp bs,
    float* __restrict__ q, u16* __restrict__ kvp16, float* __restrict__ skb) {
    constexpr int NTK = K / 32;
    int wave = threadIdx.x >> 6;  // 0:q 1:k 2:v 3:skip
    int l = threadIdx.x & 63;
    int lr = l & 15, lg = l >> 4;
    int row0 = blockIdx.x * 32;
    short8v a[2][NTK];
#pragma unroll
    for (int mi = 0; mi < 2; ++mi)
#pragma unroll
        for (int tk = 0; tk < NTK; ++tk)
            a[mi][tk] = *reinterpret_cast<const short8v*>(
                &A[(size_t)(row0 + mi * 16 + lr) * K + tk * 32 + lg * 8]);
    f32x4 c[2][4] = {};
#pragma unroll
    for (int tn = 0; tn < 4; ++tn) {
        int gtn = wave * 4 + tn;
#pragma unroll
        for (int tk = 0; tk < NTK; ++tk) {
            short8v b = *reinterpret_cast<const short8v*>(&Bp[((size_t)(tk * 16 + gtn) * 64 + l) * 8]);
            c[0][tn] = __builtin_amdgcn_mfma_f32_16x16x32_bf16(a[0][tk], b, c[0][tn], 0, 0, 0);
            c[1][tn] = __builtin_amdgcn_mfma_f32_16x16x32_bf16(a[1][tk], b, c[1][tn], 0, 0, 0);
        }
    }
    fp bias = wave == 0 ? bq : wave == 1 ? bk : wave == 2 ? bv : bs;
#pragma unroll
    for (int tn = 0; tn < 4; ++tn) {
        int cl = tn * 16 + lr;
        float bb = bias[cl];
#pragma unroll
        for (int mi = 0; mi < 2; ++mi)
#pragma unroll
            for (int r = 0; r < 4; ++r) {
                size_t row = row0 + mi * 16 + lg * 4 + r;
                float val = c[mi][tn][r] + bb;
                if (wave == 0) q[row * 64 + cl] = val * 0.125f;
                else if (wave == 3) skb[row * 64 + cl] = val;
                else if (wave == 1) kvp16[(row * 64 + cl) * 2] = rne_bf16(val);      // k -> low half
                else kvp16[(row * 64 + cl) * 2 + 1] = rne_bf16(val);                 // v -> high half
            }
    }
}

// ---------------- per-node edge aggregation: 16-lane groups, packed kv, bf16 ea, inline qwe ----------------
__global__ __launch_bounds__(256) void node_kernel(
    const float* __restrict__ qs, const u32* __restrict__ kvp,
    const float* __restrict__ skb, const uint4* __restrict__ eab, fp We,
    const int* __restrict__ row_ptr, const int* __restrict__ csr_src,
    u16* __restrict__ hb, float* __restrict__ hmax, int act, int initmax) {
    int tid = threadIdx.x;
    int lane = tid & 63;
    int g = lane >> 4, fl = lane & 15;
    int gbase = g << 4;
    int n = blockIdx.x * 16 + (tid >> 6) * 4 + g;
    int f0 = fl * 4;
    float4 q4 = *reinterpret_cast<const float4*>(&qs[(size_t)n * 64 + f0]);
    // inline qwe: qw[c] = sum_f q[f]*We[c][f] (q prescaled 1/8)
    float qw[7];
#pragma unroll
    for (int c = 0; c < 7; ++c) {
        float4 w4 = *reinterpret_cast<const float4*>(&We[c * 64 + f0]);
        float t = q4.x * w4.x + q4.y * w4.y + q4.z * w4.z + q4.w * w4.w;
        t += __shfl_xor(t, 1);
        t += __shfl_xor(t, 2);
        t += __shfl_xor(t, 4);
        t += __shfl_xor(t, 8);
        qw[c] = t;
    }
    int beg = row_ptr[n], end = row_ptr[n + 1];
    float s = 0.f;
    float ax = 0.f, ay = 0.f, az = 0.f, aw = 0.f;
    float r[7];
#pragma unroll
    for (int c = 0; c < 7; ++c) r[c] = 0.f;

    for (int p = beg; p < end; p += 4) {
        int svi = p + (fl & 3);
        svi = svi < end ? svi : end - 1;
        int sv = csr_src[svi];
#pragma unroll
        for (int j = 0; j < 4; ++j) {
            int pj = p + j;
            int pc = pj < end ? pj : end - 1;
            int sn = __shfl(sv, gbase + j);
            uint4 kv4 = *reinterpret_cast<const uint4*>(&kvp[(size_t)sn * 64 + f0]);
            uint4 e4 = eab[pc];
            float e0 = bf16lo_f(e4.x), e1 = bf16hi_f(e4.x);
            float e2 = bf16lo_f(e4.y), e3 = bf16hi_f(e4.y);
            float e4f = bf16lo_f(e4.z), e5 = bf16hi_f(e4.z);
            float e6 = bf16lo_f(e4.w);
            float al = qw[0] * e0 + qw[1] * e1 + qw[2] * e2 + qw[3] * e3 +
                       qw[4] * e4f + qw[5] * e5 + qw[6] * e6;
            float kf0 = bf16lo_f(kv4.x), vf0 = bf16hi_f(kv4.x);
            float kf1 = bf16lo_f(kv4.y), vf1 = bf16hi_f(kv4.y);
            float kf2 = bf16lo_f(kv4.z), vf2 = bf16hi_f(kv4.z);
            float kf3 = bf16lo_f(kv4.w), vf3 = bf16hi_f(kv4.w);
            float d = q4.x * kf0 + q4.y * kf1 + q4.z * kf2 + q4.w * kf3;
            d += __shfl_xor(d, 1);
            d += __shfl_xor(d, 2);
            d += __shfl_xor(d, 4);
            d += __shfl_xor(d, 8);
            float pe = (pj < end) ? __expf(al + d) : 0.f;
            s += pe;
            ax += pe * vf0; ay += pe * vf1; az += pe * vf2; aw += pe * vf3;
            r[0] += pe * e0; r[1] += pe * e1; r[2] += pe * e2; r[3] += pe * e3;
            r[4] += pe * e4f; r[5] += pe * e5; r[6] += pe * e6;
        }
    }
    float inv = 1.f / (s + 1e-16f);
    float o0 = ax, o1 = ay, o2 = az, o3 = aw;
#pragma unroll
    for (int c = 0; c < 7; ++c) {
        o0 += We[c * 64 + f0 + 0] * r[c];
        o1 += We[c * 64 + f0 + 1] * r[c];
        o2 += We[c * 64 + f0 + 2] * r[c];
        o3 += We[c * 64 + f0 + 3] * r[c];
    }
    float4 sk4 = *reinterpret_cast<const float4*>(&skb[(size_t)n * 64 + f0]);
    float4 res;
    res.x = o0 * inv + sk4.x;
    res.y = o1 * inv + sk4.y;
    res.z = o2 * inv + sk4.z;
    res.w = o3 * inv + sk4.w;
    if (act) {
        res.x = res.x > 0.f ? res.x : (__expf(res.x) - 1.f);
        res.y = res.y > 0.f ? res.y : (__expf(res.y) - 1.f);
        res.z = res.z > 0.f ? res.z : (__expf(res.z) - 1.f);
        res.w = res.w > 0.f ? res.w : (__expf(res.w) - 1.f);
    }
    ushort4 hb4;
    hb4.x = rne_bf16(res.x); hb4.y = rne_bf16(res.y); hb4.z = rne_bf16(res.z); hb4.w = rne_bf16(res.w);
    *reinterpret_cast<ushort4*>(&hb[(size_t)n * 64 + f0]) = hb4;
    if (initmax) {
        *reinterpret_cast<float4*>(&hmax[(size_t)n * 64 + f0]) = res;
    } else {
        float4 hm = *reinterpret_cast<const float4*>(&hmax[(size_t)n * 64 + f0]);
        hm.x = fmaxf(hm.x, res.x);
        hm.y = fmaxf(hm.y, res.y);
        hm.z = fmaxf(hm.z, res.z);
        hm.w = fmaxf(hm.w, res.w);
        *reinterpret_cast<float4*>(&hmax[(size_t)n * 64 + f0]) = hm;
    }
}

// ---------------- gate MLP per node ----------------
__global__ __launch_bounds__(256) void gate_kernel(const float* __restrict__ h, fp g1W, fp g1b, fp g2W,
                                                   fp g2b, float* __restrict__ gate) {
    __shared__ float hs[4][64];
    int w = threadIdx.x >> 6, lane = threadIdx.x & 63;
    int n = blockIdx.x * 4 + w;
    hs[w][lane] = h[(size_t)n * 64 + lane];
    __syncthreads();
    float a = 0.f;
    for (int f = 0; f < 64; ++f) a += hs[w][f] * g1W[f * 64 + lane];
    a = fmaxf(a + g1b[lane], 0.f);
    float val = a * g2W[lane];
#pragma unroll
    for (int off = 32; off; off >>= 1) val += __shfl_xor(val, off);
    if (lane == 0) gate[n] = val + g2b[0];
}

// ---------------- graph boundaries ----------------
__global__ __launch_bounds__(256) void starts_kernel(const int* __restrict__ batch, int* __restrict__ starts) {
    int i = blockIdx.x * 256 + threadIdx.x;
    if (i >= N_NODES) return;
    if (i == 0) {
        int b = batch[0];
        for (int g = 0; g <= b && g <= N_GRAPHS; ++g) starts[g] = 0;
    } else {
        int b0 = batch[i - 1], b1 = batch[i];
        for (int g = b0 + 1; g <= b1 && g <= N_GRAPHS; ++g) starts[g] = i;
    }
    if (i == N_NODES - 1) {
        int b = batch[i];
        for (int g = b + 1; g <= N_GRAPHS; ++g) starts[g] = N_NODES;
    }
}

// ---------------- gated softmax pooling ----------------
__global__ __launch_bounds__(256) void pool_kernel(const float* __restrict__ h, const float* __restrict__ gate,
                                                   const int* __restrict__ starts, float* __restrict__ pooled) {
    int g = blockIdx.x;
    int beg = starts[g], end = starts[g + 1];
    int tid = threadIdx.x, lane = tid & 63, w = tid >> 6;
    __shared__ float red[4];
    __shared__ float accs[4][64];
    float m = -INFINITY;
    for (int i = beg + tid; i < end; i += 256) m = fmaxf(m, gate[i]);
#pragma unroll
    for (int off = 32; off; off >>= 1) m = fmaxf(m, __shfl_xor(m, off));
    if (lane == 0) red[w] = m;
    __syncthreads();
    m = fmaxf(fmaxf(red[0], red[1]), fmaxf(red[2], red[3]));
    __syncthreads();
    float s = 0.f;
    for (int i = beg + tid; i < end; i += 256) s += __expf(gate[i] - m);
#pragma unroll
    for (int off = 32; off; off >>= 1) s += __shfl_xor(s, off);
    if (lane == 0) red[w] = s;
    __syncthreads();
    s = red[0] + red[1] + red[2] + red[3] + 1e-16f;
    float acc = 0.f;
    for (int i = beg + w; i < end; i += 4) {
        float p = __expf(gate[i] - m);
        acc += p * h[(size_t)i * 64 + lane];
    }
    accs[w][lane] = acc;
    __syncthreads();
    if (w == 0) pooled[g * 64 + lane] = (accs[0][lane] + accs[1][lane] + accs[2][lane] + accs[3][lane]) / s;
}

// ---------------- 6-expert MLP head (f32 output) ----------------
__global__ __launch_bounds__(256) void mlp_kernel(const float* __restrict__ pooled, fp m0W, fp m0b, fp m1W,
                                                  fp m1b, fp m2W, fp m2b, fp m3W, fp m3b,
                                                  float* __restrict__ out) {
    int e = blockIdx.x, tid = threadIdx.x;
    __shared__ float P[64 * 64];
    __shared__ float A1[64 * 32];
    __shared__ float A2[64 * 16];
    __shared__ float A3[64 * 8];
    for (int i = tid; i < 64 * 64; i += 256) P[i] = pooled[i];
    __syncthreads();
    fp W0 = m0W + e * 64 * 32; fp B0 = m0b + e * 32;
    for (int i = tid; i < 64 * 32; i += 256) {
        int g = i >> 5, c = i & 31;
        float a = B0[c];
        for (int f = 0; f < 64; ++f) a += P[g * 64 + f] * W0[f * 32 + c];
        A1[i] = a > 0.f ? a : (__expf(a) - 1.f);
    }
    __syncthreads();
    fp W1 = m1W + e * 32 * 16; fp B1 = m1b + e * 16;
    for (int i = tid; i < 64 * 16; i += 256) {
        int g = i >> 4, c = i & 15;
        float a = B1[c];
        for (int f = 0; f < 32; ++f) a += A1[g * 32 + f] * W1[f * 16 + c];
        A2[i] = a > 0.f ? a : (__expf(a) - 1.f);
    }
    __syncthreads();
    fp W2 = m2W + e * 16 * 8; fp B2 = m2b + e * 8;
    for (int i = tid; i < 64 * 8; i += 256) {
        int g = i >> 3, c = i & 7;
        float a = B2[c];
        for (int f = 0; f < 16; ++f) a += A2[g * 16 + f] * W2[f * 8 + c];
        A3[i] = a > 0.f ? a : (__expf(a) - 1.f);
    }
    __syncthreads();
    fp W3 = m3W + e * 8;
    if (tid < 64) {
        int g = tid;
        float a = m3b[e];
        for (int j = 0; j < 8; ++j) a += A3[g * 8 + j] * W3[j];
        out[g * 6 + e] = a;
    }
}

__global__ __launch_bounds__(64) void loss_kernel(const float* __restrict__ preds, fp y,
                                                  float* __restrict__ out) {
    int lane = threadIdx.x;
    float lsum = 0.f;
    if (lane < 6) {
        float acc = 0.f;
        for (int g = 0; g < 64; ++g) {
            float d = preds[g * 6 + lane] - y[g * 6 + lane];
            acc += d * d;
        }
        lsum = sqrtf(acc / 64.f);
    }
#pragma unroll
    for (int off = 32; off; off >>= 1) lsum += __shfl_xor(lsum, off);
    if (lane == 0) out[384] = lsum;
}

extern "C" void kernel_launch(void* const* d_in, const int* in_sizes, int n_in, void* d_out, int out_size,
                              void* d_ws, size_t ws_size, hipStream_t stream) {
    bool dictOrder = (in_sizes[1] == 2 * N_EDGES);
    int iEI = dictOrder ? 1 : 33;
    int iEA = dictOrder ? 2 : 1;
    int iBT = dictOrder ? 3 : 34;
    int iY  = dictOrder ? 4 : 2;
    int w0  = dictOrder ? 5 : 3;

    fp x = (fp)d_in[0];
    const int* ei = (const int*)d_in[iEI];
    fp eattr = (fp)d_in[iEA];
    const int* batch = (const int*)d_in[iBT];
    fp y = (fp)d_in[iY];
    fp Wq0 = (fp)d_in[w0 + 0], bq0 = (fp)d_in[w0 + 1], Wk0 = (fp)d_in[w0 + 2], bk0 = (fp)d_in[w0 + 3];
    fp Wv0 = (fp)d_in[w0 + 4], bv0 = (fp)d_in[w0 + 5], We0 = (fp)d_in[w0 + 6];
    fp Ws0 = (fp)d_in[w0 + 7], bs0 = (fp)d_in[w0 + 8];
    fp Wq = (fp)d_in[w0 + 9], bq = (fp)d_in[w0 + 10], Wk = (fp)d_in[w0 + 11], bk = (fp)d_in[w0 + 12];
    fp Wv = (fp)d_in[w0 + 13], bv = (fp)d_in[w0 + 14], Wel = (fp)d_in[w0 + 15];
    fp Ws = (fp)d_in[w0 + 16], bs = (fp)d_in[w0 + 17];
    fp g1W = (fp)d_in[w0 + 18], g1b = (fp)d_in[w0 + 19], g2W = (fp)d_in[w0 + 20], g2b = (fp)d_in[w0 + 21];
    fp m0W = (fp)d_in[w0 + 22], m0b = (fp)d_in[w0 + 23], m1W = (fp)d_in[w0 + 24], m1b = (fp)d_in[w0 + 25];
    fp m2W = (fp)d_in[w0 + 26], m2b = (fp)d_in[w0 + 27], m3W = (fp)d_in[w0 + 28], m3b = (fp)d_in[w0 + 29];

    const int* srcArr = ei;
    const int* dstArr = ei + N_EDGES;

    char* wsp = (char*)d_ws;
    auto alloc = [&](size_t bytes) -> void* {
        void* p = (void*)wsp;
        wsp += (bytes + 255) & ~(size_t)255;
        return p;
    };
    float* q = (float*)alloc((size_t)N_NODES * 64 * 4);      // prescaled 1/8
    u32* kvp = (u32*)alloc((size_t)N_NODES * 64 * 4);        // packed bf16 k|v<<16 per feature
    float* skb = (float*)alloc((size_t)N_NODES * 64 * 4);
    u16* hb = (u16*)alloc((size_t)N_NODES * 64 * 2);         // h bf16 (gemm A for layers 1-3)
    u16* xb = (u16*)alloc((size_t)N_NODES * IN_CH * 2);      // x bf16
    float* hmax = (float*)alloc((size_t)N_NODES * 64 * 4);
    float* gate = (float*)alloc((size_t)N_NODES * 4);
    float* pooled = (float*)alloc(64 * 64 * 4);
    int* row_ptr = (int*)alloc((N_NODES + 1) * 4);
    int* cursor = (int*)alloc((size_t)N_NODES * 4);
    int* csr_src = (int*)alloc((size_t)N_EDGES * 4);
    uint4* eab = (uint4*)alloc((size_t)N_EDGES * 16);
    uint4* eab_orig = (uint4*)alloc((size_t)N_EDGES * 16);
    u16* Bp0 = (u16*)alloc((size_t)(IN_CH / 32) * 16 * 512 * 2);
    u16* Bp1 = (u16*)alloc((size_t)(DIM / 32) * 16 * 512 * 2);
    u16* Bp2 = (u16*)alloc((size_t)(DIM / 32) * 16 * 512 * 2);
    u16* Bp3 = (u16*)alloc((size_t)(DIM / 32) * 16 * 512 * 2);
    int* blksum = (int*)alloc(256 * 4);
    int* starts = (int*)alloc((N_GRAPHS + 1) * 4);
    (void)ws_size;
    (void)n_in;

    float* outF = (float*)d_out;  // [0..383] preds, [384] total_loss

    // ---- CSR build (by dst) + weight/x conversion ----
    hipMemsetAsync(cursor, 0, (size_t)N_NODES * 4, stream);
    count_kernel<<<(N_EDGES + 255) / 256, 256, 0, stream>>>(dstArr, cursor);
    scan1_kernel<<<NBLK, 512, 0, stream>>>(cursor, row_ptr, blksum);
    scan2_kernel<<<1, 256, 0, stream>>>(blksum);
    scan3_kernel<<<NBLK, 512, 0, stream>>>(row_ptr, blksum, cursor);
    cvt_ea_kernel<<<(N_EDGES + 255) / 256, 256, 0, stream>>>(eattr, eab_orig);
    for (int p = 0; p < NPASS; ++p)
        scatter_pass_kernel<<<(N_EDGES + 255) / 256, 256, 0, stream>>>(
            srcArr, dstArr, eab_orig, cursor, csr_src, eab, p * PASS_SZ, (p + 1) * PASS_SZ);
    cvt_bf16_kernel<<<(N_NODES * IN_CH / 4 + 255) / 256, 256, 0, stream>>>(x, xb, N_NODES * IN_CH / 4);
    packW_kernel<<<((IN_CH / 32) * 16 * 512 + 255) / 256, 256, 0, stream>>>(Wq0, Wk0, Wv0, Ws0, Bp0, IN_CH);
    u16* Bps[3] = {Bp1, Bp2, Bp3};
    for (int i = 0; i < N_CONVS; ++i)
        packW_kernel<<<((DIM / 32) * 16 * 512 + 255) / 256, 256, 0, stream>>>(
            Wq + i * 4096, Wk + i * 4096, Wv + i * 4096, Ws + i * 4096, Bps[i], DIM);

    int nodeGrid = N_NODES / 16;
    // layer 0 (conv_first, 128 -> 64), ELU, init hmax
    gemm_mfma_kernel<IN_CH><<<N_NODES / 32, 256, 0, stream>>>(xb, Bp0, bq0, bk0, bv0, bs0, q, (u16*)kvp, skb);
    node_kernel<<<nodeGrid, 256, 0, stream>>>(q, kvp, skb, eab, We0, row_ptr, csr_src, hb, hmax, 1, 1);
    // layers 1..3 (64 -> 64); ELU except last; JK running max
    for (int i = 0; i < N_CONVS; ++i) {
        gemm_mfma_kernel<DIM><<<N_NODES / 32, 256, 0, stream>>>(hb, Bps[i], bq + i * 64, bk + i * 64,
                                                                bv + i * 64, bs + i * 64, q, (u16*)kvp, skb);
        node_kernel<<<nodeGrid, 256, 0, stream>>>(q, kvp, skb, eab, Wel + i * 448, row_ptr,
                                                  csr_src, hb, hmax, (i < N_CONVS - 1) ? 1 : 0, 0);
    }
    // pooling head
    gate_kernel<<<N_NODES / 4, 256, 0, stream>>>(hmax, g1W, g1b, g2W, g2b, gate);
    starts_kernel<<<(N_NODES + 255) / 256, 256, 0, stream>>>(batch, starts);
    pool_kernel<<<N_GRAPHS, 256, 0, stream>>>(hmax, gate, starts, pooled);
    mlp_kernel<<<6, 256, 0, stream>>>(pooled, m0W, m0b, m1W, m1b, m2W, m2b, m3W, m3b, outF);
    loss_kernel<<<1, 64, 0, stream>>>(outF, y, outF);
}